// Round 1
// baseline (7514.393 us; speedup 1.0000x reference)
//
#include <hip/hip_runtime.h>
#include <math.h>

// ---------------- problem constants ----------------
#define TTD 1024       // T
#define DDM 1024       // D
#define NHR 32         // HKV*R heads
#define HDIM 64        // head dim
#define NOUTW 4096     // OUTW
#define PSCALE 0.125f  // HD^-0.5
#define NG 8           // heads per group (memory/launch tradeoff)

// ---------------- workspace layout (floats) ----------------
// total = 37,322,752 floats = 142.4 MiB  (requires ws_size >= ~150 MB)
#define OFF_Q    0L
#define OFF_K    (OFF_Q    + (long)TTD*DDM)
#define OFF_V    (OFF_K    + (long)TTD*DDM)
#define OFF_BTL  (OFF_V    + (long)TTD*DDM)
#define OFF_WLOW (OFF_BTL  + (long)TTD*NHR)
#define OFF_WRAW (OFF_WLOW + (long)TTD*32)
#define OFF_WH   (OFF_WRAW + (long)TTD*NOUTW)
#define OFF_BETA (OFF_WH   + (long)NHR*TTD*HDIM)
#define OFF_OALL (OFF_BETA + (long)NHR*TTD)
#define OFF_BG   (OFF_OALL + (long)TTD*2048)
#define OFF_PT   (OFF_BG   + (long)NG*TTD*TTD)
#define OFF_QW   (OFF_PT   + (long)NG*TTD*HDIM)
#define OFF_LG   (OFF_QW   + (long)NG*TTD*TTD)

// mask modes for pairdot64
#define PD_PLAIN 0
#define PD_STRICT_BETA 1   // C = (r>c) ? beta[r]*acc : 0
#define PD_INCL 2          // C = (r>=c) ? acc : 0
#define PD_APPLY 3         // C -= beta[r]*acc
// tile skip modes
#define SK_NONE 0
#define SK_SKIP 1          // upper tiles never read later
#define SK_ZERO 2          // upper tiles must be zero-filled
// gemm_nn modes
#define NN_SUB_TRI 1       // C -= acc, skip upper tiles, K in [cn, rm+64)
#define NN_SET_TRI 2       // C  = acc, K in [0, rm+64)

__device__ __forceinline__ const float* head_ptr(const float* p, long hs, int hmode, int hg, int h) {
  long idx = (hmode == 0) ? (long)hg : (hmode == 1) ? (long)h : (long)(h >> 1);
  return p + idx * hs;
}

// ---------------- generic NT GEMM: C[m,n] = sum_k A[m,k]*B[n,k] ----------------
__global__ __launch_bounds__(256) void gemm_nt_kernel(
    const float* __restrict__ A, int lda,
    const float* __restrict__ B, int ldb,
    float* __restrict__ C, int ldc,
    int N, int K)
{
  __shared__ float As[64][33];
  __shared__ float Bs[64][33];
  int tid = threadIdx.x;
  int tx = tid & 15, ty = tid >> 4;
  int rm = blockIdx.y * 64, cn = blockIdx.x * 64;
  float acc[4][4] = {};
  for (int k0 = 0; k0 < K; k0 += 32) {
    #pragma unroll
    for (int i = 0; i < 8; ++i) {
      int e = tid + i * 256;
      int r = e >> 5, c = e & 31;
      As[r][c] = A[(long)(rm + r) * lda + k0 + c];
      float bv = 0.f;
      if (cn + r < N) bv = B[(long)(cn + r) * ldb + k0 + c];
      Bs[r][c] = bv;
    }
    __syncthreads();
    #pragma unroll
    for (int kk = 0; kk < 32; ++kk) {
      float a[4], b[4];
      #pragma unroll
      for (int u = 0; u < 4; ++u) a[u] = As[ty * 4 + u][kk];
      #pragma unroll
      for (int v = 0; v < 4; ++v) b[v] = Bs[tx * 4 + v][kk];
      #pragma unroll
      for (int u = 0; u < 4; ++u)
        #pragma unroll
        for (int v = 0; v < 4; ++v)
          acc[u][v] += a[u] * b[v];
    }
    __syncthreads();
  }
  #pragma unroll
  for (int u = 0; u < 4; ++u) {
    int r = rm + ty * 4 + u;
    #pragma unroll
    for (int v = 0; v < 4; ++v) {
      int c = cn + tx * 4 + v;
      if (c < N) C[(long)r * ldc + c] = acc[u][v];
    }
  }
}

// ---------------- headed K=64 pair-dot: C[r,c] = f(sum_d A[r,d]*B[c,d]) ----------------
__global__ __launch_bounds__(256) void pairdot64_kernel(
    const float* __restrict__ A, long a_hs, int a_hmode, int lda,
    const float* __restrict__ B, long b_hs, int b_hmode, int ldb,
    float* __restrict__ C, long c_hs, int c_hmode, int ldc,
    const float* __restrict__ beta, // per-head stride TTD, global-head indexed; may be null
    int row0, int col0, int mode, int skip_mode, int head0)
{
  int hg = blockIdx.z;
  int h = head0 + hg;
  int rm = row0 + blockIdx.y * 64;
  int cn = col0 + blockIdx.x * 64;
  int tid = threadIdx.x;

  if (skip_mode != SK_NONE && cn >= rm + 64) {
    if (skip_mode == SK_ZERO) {
      float* Ch = (float*)head_ptr(C, c_hs, c_hmode, hg, h);
      #pragma unroll
      for (int i = 0; i < 16; ++i) {
        int e = tid + i * 256;
        int r = e >> 6, c = e & 63;
        Ch[(long)(rm + r) * ldc + cn + c] = 0.f;
      }
    }
    return;
  }

  const float* Ah = head_ptr(A, a_hs, a_hmode, hg, h);
  const float* Bh = head_ptr(B, b_hs, b_hmode, hg, h);
  float* Ch = (float*)head_ptr(C, c_hs, c_hmode, hg, h);
  const float* betah = beta ? beta + (long)h * TTD : nullptr;

  __shared__ float As[64][65];
  __shared__ float Bs[64][65];
  int tx = tid & 15, ty = tid >> 4;
  #pragma unroll
  for (int i = 0; i < 16; ++i) {
    int e = tid + i * 256;
    int r = e >> 6, c = e & 63;
    As[r][c] = Ah[(long)(rm + r) * lda + c];
    Bs[r][c] = Bh[(long)(cn + r) * ldb + c];
  }
  __syncthreads();
  float acc[4][4] = {};
  #pragma unroll
  for (int kk = 0; kk < 64; ++kk) {
    float a[4], b[4];
    #pragma unroll
    for (int u = 0; u < 4; ++u) a[u] = As[ty * 4 + u][kk];
    #pragma unroll
    for (int v = 0; v < 4; ++v) b[v] = Bs[tx * 4 + v][kk];
    #pragma unroll
    for (int u = 0; u < 4; ++u)
      #pragma unroll
      for (int v = 0; v < 4; ++v)
        acc[u][v] += a[u] * b[v];
  }
  #pragma unroll
  for (int u = 0; u < 4; ++u) {
    int r = rm + ty * 4 + u;
    #pragma unroll
    for (int v = 0; v < 4; ++v) {
      int c = cn + tx * 4 + v;
      long off = (long)r * ldc + c;
      if (mode == PD_APPLY) {
        Ch[off] -= betah[r] * acc[u][v];
      } else {
        float val = acc[u][v];
        if (mode == PD_STRICT_BETA) val = (r > c) ? val * betah[r] : 0.f;
        else if (mode == PD_INCL)   val = (r >= c) ? val : 0.f;
        Ch[off] = val;
      }
    }
  }
}

// ---------------- headed NN GEMM: C[r,c] (-)= sum_k A[r,k]*B[k,c] ----------------
__global__ __launch_bounds__(256) void gemm_nn_headed_kernel(
    const float* __restrict__ A, long a_hs, int a_hmode, int lda,
    const float* __restrict__ B, long b_hs, int b_hmode, int ldb,
    float* __restrict__ C, long c_hs, int c_hmode, int ldc,
    int K, int mode, int head0)
{
  int hg = blockIdx.z;
  int h = head0 + hg;
  int rm = blockIdx.y * 64, cn = blockIdx.x * 64;
  int kstart = 0, kend = K;
  if (mode == NN_SUB_TRI) {
    if (cn >= rm + 64) return;
    kstart = cn;
    kend = min(K, rm + 64);
  } else { // NN_SET_TRI
    kend = min(K, rm + 64);
  }
  const float* Ah = head_ptr(A, a_hs, a_hmode, hg, h);
  const float* Bh = head_ptr(B, b_hs, b_hmode, hg, h);
  float* Ch = (float*)head_ptr(C, c_hs, c_hmode, hg, h);

  __shared__ float As[64][33];  // r x k
  __shared__ float Bs[32][65];  // k x c
  int tid = threadIdx.x;
  int tx = tid & 15, ty = tid >> 4;
  float acc[4][4] = {};
  for (int k0 = kstart; k0 < kend; k0 += 32) {
    #pragma unroll
    for (int i = 0; i < 8; ++i) {
      int e = tid + i * 256;
      int r = e >> 5, c = e & 31;
      As[r][c] = Ah[(long)(rm + r) * lda + k0 + c];
      int kk = e >> 6, cc = e & 63;
      Bs[kk][cc] = Bh[(long)(k0 + kk) * ldb + cn + cc];
    }
    __syncthreads();
    #pragma unroll
    for (int kk = 0; kk < 32; ++kk) {
      float a[4], b[4];
      #pragma unroll
      for (int u = 0; u < 4; ++u) a[u] = As[ty * 4 + u][kk];
      #pragma unroll
      for (int v = 0; v < 4; ++v) b[v] = Bs[kk][tx * 4 + v];
      #pragma unroll
      for (int u = 0; u < 4; ++u)
        #pragma unroll
        for (int v = 0; v < 4; ++v)
          acc[u][v] += a[u] * b[v];
    }
    __syncthreads();
  }
  #pragma unroll
  for (int u = 0; u < 4; ++u) {
    int r = rm + ty * 4 + u;
    #pragma unroll
    for (int v = 0; v < 4; ++v) {
      int c = cn + tx * 4 + v;
      long off = (long)r * ldc + c;
      if (mode == NN_SUB_TRI) Ch[off] -= acc[u][v];
      else Ch[off] = acc[u][v];
    }
  }
}

// ---------------- diagonal-block forward substitution (unit lower) ----------------
// Solves rows [r0, r0+64) of (I + Mw) Bmat = rhs in-place for all columns this block covers.
// Mw[t][s] = beta[t] * dot(wh[t], wh[s]) computed on the fly.
__global__ __launch_bounds__(256) void diag_solve_kernel(
    float* __restrict__ Bmat, const float* __restrict__ wh,
    const float* __restrict__ beta, int r0, int head0)
{
  int hg = blockIdx.z;
  int h = head0 + hg;
  int j = blockIdx.x * 256 + threadIdx.x;
  const float* whh = wh + (long)h * TTD * HDIM + (long)r0 * HDIM;
  const float* betah = beta + (long)h * TTD + r0;
  float* Bh = Bmat + (long)hg * TTD * TTD;

  __shared__ float whL[64][65];
  __shared__ float Lm[64][65];
  __shared__ float betaL[64];
  int tid = threadIdx.x;
  #pragma unroll
  for (int i = 0; i < 16; ++i) {
    int e = tid + i * 256;
    int r = e >> 6, c = e & 63;
    whL[r][c] = whh[(long)r * HDIM + c];
  }
  if (tid < 64) betaL[tid] = betah[tid];
  __syncthreads();
  #pragma unroll
  for (int i = 0; i < 16; ++i) {
    int e = tid + i * 256;
    int t = e >> 6, s = e & 63;
    if (s < t) {
      float d = 0.f;
      #pragma unroll
      for (int kk = 0; kk < 64; ++kk) d += whL[t][kk] * whL[s][kk];
      Lm[t][s] = betaL[t] * d;
    }
  }
  __syncthreads();

  float cur[64];
  #pragma unroll
  for (int t = 0; t < 64; ++t) cur[t] = Bh[(long)(r0 + t) * TTD + j];
  #pragma unroll
  for (int t = 0; t < 64; ++t) {
    float bv = cur[t];
    Bh[(long)(r0 + t) * TTD + j] = bv;
    #pragma unroll
    for (int u = t + 1; u < 64; ++u) cur[u] -= Lm[u][t] * bv;
  }
}

// ---------------- panel: Pt[j][d] = sum_{s in [r0,r0+64)} Bmat[s][j] * wh[s][d] ----------------
__global__ __launch_bounds__(256) void panel_kernel(
    const float* __restrict__ Bmat, const float* __restrict__ wh,
    float* __restrict__ Pt, int r0, int head0)
{
  int hg = blockIdx.z;
  int h = head0 + hg;
  int j0 = blockIdx.x * 64;
  const float* Bh = Bmat + (long)hg * TTD * TTD + (long)r0 * TTD;
  const float* whh = wh + (long)h * TTD * HDIM + (long)r0 * HDIM;
  float* Pth = Pt + (long)hg * TTD * HDIM;

  __shared__ float Bs[64][65];  // s x j
  __shared__ float Ws[64][65];  // s x d
  int tid = threadIdx.x;
  int tx = tid & 15, ty = tid >> 4;
  #pragma unroll
  for (int i = 0; i < 16; ++i) {
    int e = tid + i * 256;
    int s = e >> 6, c = e & 63;
    Bs[s][c] = Bh[(long)s * TTD + j0 + c];
    Ws[s][c] = whh[(long)s * HDIM + c];
  }
  __syncthreads();
  float acc[4][4] = {};
  #pragma unroll
  for (int s = 0; s < 64; ++s) {
    float jv[4], dv[4];
    #pragma unroll
    for (int u = 0; u < 4; ++u) jv[u] = Bs[s][ty * 4 + u];
    #pragma unroll
    for (int v = 0; v < 4; ++v) dv[v] = Ws[s][tx * 4 + v];
    #pragma unroll
    for (int u = 0; u < 4; ++u)
      #pragma unroll
      for (int v = 0; v < 4; ++v)
        acc[u][v] += jv[u] * dv[v];
  }
  #pragma unroll
  for (int u = 0; u < 4; ++u)
    #pragma unroll
    for (int v = 0; v < 4; ++v)
      Pth[(long)(j0 + ty * 4 + u) * HDIM + tx * 4 + v] = acc[u][v];
}

// ---------------- conv(K=3 causal) + SiLU + rotation + L2-normalize -> wh[h][t][d] ----------------
__global__ __launch_bounds__(256) void convdir_kernel(
    const float* __restrict__ w_raw, const float* __restrict__ conv_w,
    const float* __restrict__ omega, const float* __restrict__ phi,
    float* __restrict__ wh)
{
  int gid = blockIdx.x * 256 + threadIdx.x;
  int lane = gid & 63;
  int w = gid >> 6;        // w = t*32 + hr
  int hr = w & 31, t = w >> 5;
  int hkv = hr >> 1, r = hr & 1;
  int cA = hkv * 256 + r * 128 + lane;
  int cB = cA + 64;
  float a = 0.f, b = 0.f;
  #pragma unroll
  for (int i = 0; i < 3; ++i) {
    int tp = t - 2 + i;
    if (tp >= 0) {
      a += w_raw[(long)tp * NOUTW + cA] * conv_w[cA * 3 + i];
      b += w_raw[(long)tp * NOUTW + cB] * conv_w[cB * 3 + i];
    }
  }
  a = a / (1.f + expf(-a));
  b = b / (1.f + expf(-b));
  float th = omega[r] * (float)t + phi[r];
  float wd = a * cosf(th) + b * sinf(th);
  float ss = wd * wd;
  #pragma unroll
  for (int o = 32; o > 0; o >>= 1) ss += __shfl_xor(ss, o, 64);
  float inv = 1.f / sqrtf(ss + 1e-6f);
  wh[((long)hr * TTD + t) * HDIM + lane] = wd * inv;
}

// ---------------- beta[hr][t] = 2*sigmoid(bt_lin[t][hr] + bt_b[hr]) ----------------
__global__ __launch_bounds__(256) void beta_kernel(
    const float* __restrict__ bt_lin, const float* __restrict__ bt_b,
    float* __restrict__ beta)
{
  int idx = blockIdx.x * 256 + threadIdx.x;
  int t = idx >> 5, hr = idx & 31;
  float x = bt_lin[t * 32 + hr] + bt_b[hr];
  beta[(long)hr * TTD + t] = 2.f / (1.f + expf(-x));
}

// ---------------- causal softmax over row i (scale applied here) ----------------
__global__ __launch_bounds__(256) void softmax_kernel(float* __restrict__ lg)
{
  int hg = blockIdx.z;
  int i = blockIdx.x;
  float* row = lg + (long)hg * TTD * TTD + (long)i * TTD;
  int n = i + 1;
  int tid = threadIdx.x;
  __shared__ float red1[4], red2[4];

  float mx = -1e30f;
  for (int j = tid; j < n; j += 256) mx = fmaxf(mx, row[j] * PSCALE);
  #pragma unroll
  for (int o = 32; o > 0; o >>= 1) mx = fmaxf(mx, __shfl_xor(mx, o, 64));
  if ((tid & 63) == 0) red1[tid >> 6] = mx;
  __syncthreads();
  mx = fmaxf(fmaxf(red1[0], red1[1]), fmaxf(red1[2], red1[3]));

  float s = 0.f;
  for (int j = tid; j < n; j += 256) s += __expf(row[j] * PSCALE - mx);
  #pragma unroll
  for (int o = 32; o > 0; o >>= 1) s += __shfl_xor(s, o, 64);
  if ((tid & 63) == 0) red2[tid >> 6] = s;
  __syncthreads();
  s = red2[0] + red2[1] + red2[2] + red2[3];
  float inv = 1.f / s;
  for (int j = tid; j < TTD; j += 256)
    row[j] = (j < n) ? __expf(row[j] * PSCALE - mx) * inv : 0.f;
}

// ---------------- host ----------------
extern "C" void kernel_launch(void* const* d_in, const int* in_sizes, int n_in,
                              void* d_out, int out_size, void* d_ws, size_t ws_size,
                              hipStream_t stream) {
  const float* hs     = (const float*)d_in[0];
  const float* q_w    = (const float*)d_in[1];
  const float* k_w    = (const float*)d_in[2];
  const float* v_w    = (const float*)d_in[3];
  const float* w1     = (const float*)d_in[4];
  const float* w2     = (const float*)d_in[5];
  const float* conv_w = (const float*)d_in[6];
  const float* bt_w   = (const float*)d_in[7];
  const float* bt_b   = (const float*)d_in[8];
  const float* o_w    = (const float*)d_in[9];
  const float* omega  = (const float*)d_in[10];
  const float* phi    = (const float*)d_in[11];
  float* out = (float*)d_out;
  float* ws = (float*)d_ws;

  float* q      = ws + OFF_Q;
  float* k      = ws + OFF_K;
  float* v      = ws + OFF_V;
  float* bt_lin = ws + OFF_BTL;
  float* w_low  = ws + OFF_WLOW;
  float* w_raw  = ws + OFF_WRAW;
  float* wh     = ws + OFF_WH;
  float* beta   = ws + OFF_BETA;
  float* o_all  = ws + OFF_OALL;
  float* B_g    = ws + OFF_BG;
  float* Pt_g   = ws + OFF_PT;
  float* qw_g   = ws + OFF_QW;
  float* lg_g   = ws + OFF_LG;

  const long TTl = (long)TTD * TTD;

  // projections
  gemm_nt_kernel<<<dim3(16, 16), 256, 0, stream>>>(hs, DDM, q_w, DDM, q, DDM, DDM, DDM);
  gemm_nt_kernel<<<dim3(16, 16), 256, 0, stream>>>(hs, DDM, k_w, DDM, k, DDM, DDM, DDM);
  gemm_nt_kernel<<<dim3(16, 16), 256, 0, stream>>>(hs, DDM, v_w, DDM, v, DDM, DDM, DDM);
  gemm_nt_kernel<<<dim3(1, 16), 256, 0, stream>>>(hs, DDM, bt_w, DDM, bt_lin, 32, 32, DDM);
  gemm_nt_kernel<<<dim3(1, 16), 256, 0, stream>>>(hs, DDM, w1, DDM, w_low, 32, 32, DDM);
  gemm_nt_kernel<<<dim3(64, 16), 256, 0, stream>>>(w_low, 32, w2, 32, w_raw, NOUTW, NOUTW, 32);
  convdir_kernel<<<dim3(8192), 256, 0, stream>>>(w_raw, conv_w, omega, phi, wh);
  beta_kernel<<<dim3(128), 256, 0, stream>>>(bt_lin, bt_b, beta);

  for (int g = 0; g < NHR / NG; ++g) {
    int head0 = g * NG;
    // rhs init: B_g[t][j] = (t>j) ? beta[t]*dot(wh[t],k[j]) : 0   (full init incl zeros)
    pairdot64_kernel<<<dim3(16, 16, NG), 256, 0, stream>>>(
        wh, (long)TTD * HDIM, 1, HDIM, k, 64L, 2, DDM,
        B_g, TTl, 0, TTD, beta, 0, 0, PD_STRICT_BETA, SK_ZERO, head0);
    // blocked forward substitution
    for (int kb = 0; kb < 16; ++kb) {
      int r0 = kb * 64;
      diag_solve_kernel<<<dim3((r0 + 64 + 255) / 256, 1, NG), 256, 0, stream>>>(
          B_g, wh, beta, r0, head0);
      if (kb < 15) {
        panel_kernel<<<dim3((r0 + 64) / 64, 1, NG), 256, 0, stream>>>(
            B_g, wh, Pt_g, r0, head0);
        pairdot64_kernel<<<dim3((r0 + 64) / 64, (TTD - r0 - 64) / 64, NG), 256, 0, stream>>>(
            wh, (long)TTD * HDIM, 1, HDIM, Pt_g, (long)TTD * HDIM, 0, HDIM,
            B_g, TTl, 0, TTD, beta, r0 + 64, 0, PD_APPLY, SK_NONE, head0);
      }
    }
    // logits = qk  (upper tiles skipped; softmax overwrites rows anyway)
    pairdot64_kernel<<<dim3(16, 16, NG), 256, 0, stream>>>(
        q, 64L, 2, DDM, k, 64L, 2, DDM,
        lg_g, TTl, 0, TTD, nullptr, 0, 0, PD_PLAIN, SK_SKIP, head0);
    // qw = incl-masked q.wh
    pairdot64_kernel<<<dim3(16, 16, NG), 256, 0, stream>>>(
        q, 64L, 2, DDM, wh, (long)TTD * HDIM, 1, HDIM,
        qw_g, TTl, 0, TTD, nullptr, 0, 0, PD_INCL, SK_SKIP, head0);
    // logits -= qw @ Bmat (triangular K-range)
    gemm_nn_headed_kernel<<<dim3(16, 16, NG), 256, 0, stream>>>(
        qw_g, TTl, 0, TTD, B_g, TTl, 0, TTD,
        lg_g, TTl, 0, TTD, TTD, NN_SUB_TRI, head0);
    softmax_kernel<<<dim3(TTD, 1, NG), 256, 0, stream>>>(lg_g);
    // o_all[:, h*64:(h+1)*64] = p @ v_head
    gemm_nn_headed_kernel<<<dim3(1, 16, NG), 256, 0, stream>>>(
        lg_g, TTl, 0, TTD, v, 64L, 2, DDM,
        o_all, 64L, 1, 2048, TTD, NN_SET_TRI, head0);
  }

  // final: out = o_all @ o_w^T
  gemm_nt_kernel<<<dim3(16, 16), 256, 0, stream>>>(o_all, 2048, o_w, 2048, out, DDM, DDM, 2048);
  (void)in_sizes; (void)n_in; (void)out_size; (void)ws_size;
}

// Round 2
// 3384.457 us; speedup vs baseline: 2.2203x; 2.2203x over previous
//
#include <hip/hip_runtime.h>
#include <math.h>

// ---------------- problem constants ----------------
#define TTD 1024
#define DDM 1024
#define NHR 32
#define HDIM 64
#define NOUTW 4096
#define PSCALE 0.125f
#define NG 8

typedef __attribute__((ext_vector_type(8))) __bf16 bf16x8;
typedef __attribute__((ext_vector_type(4))) float f32x4;
#define MFMA16(a,b,c) __builtin_amdgcn_mfma_f32_16x16x32_bf16(a,b,c,0,0,0)

__device__ __forceinline__ ushort f2b(float f) {
  unsigned u = __builtin_bit_cast(unsigned, f);
  return (ushort)((u + 0x7fffu + ((u >> 16) & 1u)) >> 16);
}

__device__ __forceinline__ void gload_lds16(const ushort* g, ushort* l) {
  __builtin_amdgcn_global_load_lds(
      (const __attribute__((address_space(1))) unsigned*)g,
      (__attribute__((address_space(3))) unsigned*)l, 16, 0, 0);
}

// ---------------- workspace layout (bytes) ----------------
#define OFF_BG    0L
#define OFF_LG    33554432L
#define OFF_WRAW  67108864L
#define OFF_WH    83886080L
#define OFF_BTL   92274688L
#define OFF_WLOW  92405760L
#define OFF_BETA  92536832L
#define OFF_HSB   92667904L
#define OFF_QWW   94765056L
#define OFF_KWW   96862208L
#define OFF_VWW   98959360L
#define OFF_W2B   101056512L
#define OFF_OWB   101318656L
#define OFF_QB    105512960L
#define OFF_KB    107610112L
#define OFF_VTB   109707264L
#define OFF_WLOWB 111804416L
#define OFF_WHB   111869952L
#define OFF_QWBUF 116064256L
#define OFF_OALL  132841472L
// end = 137,035,776 bytes (130.7 MiB) -- under the 142.4 MiB proven in R1

// ---------------- fp32 -> bf16 convert (n multiple of 1024) ----------------
__global__ __launch_bounds__(256) void cvt_kernel(const float* __restrict__ x,
                                                  ushort* __restrict__ y, long n) {
  long i = ((long)blockIdx.x * 256 + threadIdx.x) * 4;
  if (i >= n) return;
  float4 f = *(const float4*)(x + i);
  ushort4 o;
  o.x = f2b(f.x); o.y = f2b(f.y); o.z = f2b(f.z); o.w = f2b(f.w);
  *(ushort4*)(y + i) = o;
}

// ---------------- old fp32 NT GEMM (kept for tiny N=32 GEMMs) ----------------
__global__ __launch_bounds__(256) void gemm_nt_kernel(
    const float* __restrict__ A, int lda,
    const float* __restrict__ B, int ldb,
    float* __restrict__ C, int ldc,
    int N, int K)
{
  __shared__ float As[64][33];
  __shared__ float Bs[64][33];
  int tid = threadIdx.x;
  int tx = tid & 15, ty = tid >> 4;
  int rm = blockIdx.y * 64, cn = blockIdx.x * 64;
  float acc[4][4] = {};
  for (int k0 = 0; k0 < K; k0 += 32) {
    #pragma unroll
    for (int i = 0; i < 8; ++i) {
      int e = tid + i * 256;
      int r = e >> 5, c = e & 31;
      As[r][c] = A[(long)(rm + r) * lda + k0 + c];
      float bv = 0.f;
      if (cn + r < N) bv = B[(long)(cn + r) * ldb + k0 + c];
      Bs[r][c] = bv;
    }
    __syncthreads();
    #pragma unroll
    for (int kk = 0; kk < 32; ++kk) {
      float a[4], b[4];
      #pragma unroll
      for (int u = 0; u < 4; ++u) a[u] = As[ty * 4 + u][kk];
      #pragma unroll
      for (int v = 0; v < 4; ++v) b[v] = Bs[tx * 4 + v][kk];
      #pragma unroll
      for (int u = 0; u < 4; ++u)
        #pragma unroll
        for (int v = 0; v < 4; ++v)
          acc[u][v] += a[u] * b[v];
    }
    __syncthreads();
  }
  #pragma unroll
  for (int u = 0; u < 4; ++u) {
    int r = rm + ty * 4 + u;
    #pragma unroll
    for (int v = 0; v < 4; ++v) {
      int c = cn + tx * 4 + v;
      if (c < N) C[(long)r * ldc + c] = acc[u][v];
    }
  }
}

// ---------------- MFMA NT GEMM, 64x64 tile: C[m][n] = sum_k A[m][k]*B[n][k] ----------------
#define ONT_F32  0
#define ONT_B16  1
#define ONT_B16T 2
__global__ __launch_bounds__(256) void mfma_nt_kernel(
    const ushort* __restrict__ A, int lda,
    const ushort* __restrict__ B, int ldb,
    void* __restrict__ C, int ldc, int K, int outmode)
{
  __shared__ ushort As[64 * 32];
  __shared__ ushort Bs[64 * 32];
  int tid = threadIdx.x, w = tid >> 6, l = tid & 63;
  int quad = l >> 4, lane15 = l & 15;
  int rm = blockIdx.y * 64, cn = blockIdx.x * 64;
  int row = tid >> 2, ch = (tid & 3) * 8;
  f32x4 acc[4] = {};
  for (int k0 = 0; k0 < K; k0 += 32) {
    gload_lds16(A + (long)(rm + row) * lda + k0 + ch, &As[tid * 8]);
    gload_lds16(B + (long)(cn + row) * ldb + k0 + ch, &Bs[tid * 8]);
    __syncthreads();
    bf16x8 af = *(const bf16x8*)&As[(w * 16 + lane15) * 32 + quad * 8];
    #pragma unroll
    for (int f = 0; f < 4; ++f) {
      bf16x8 bf = *(const bf16x8*)&Bs[(f * 16 + lane15) * 32 + quad * 8];
      acc[f] = MFMA16(af, bf, acc[f]);
    }
    __syncthreads();
  }
  int orow = rm + w * 16 + quad * 4;
  if (outmode == ONT_F32) {
    float* Cf = (float*)C;
    #pragma unroll
    for (int f = 0; f < 4; ++f)
      #pragma unroll
      for (int r = 0; r < 4; ++r)
        Cf[(long)(orow + r) * ldc + cn + f * 16 + lane15] = acc[f][r];
  } else if (outmode == ONT_B16) {
    ushort* Cb = (ushort*)C;
    #pragma unroll
    for (int f = 0; f < 4; ++f)
      #pragma unroll
      for (int r = 0; r < 4; ++r)
        Cb[(long)(orow + r) * ldc + cn + f * 16 + lane15] = f2b(acc[f][r]);
  } else {
    ushort* Cb = (ushort*)C;
    #pragma unroll
    for (int f = 0; f < 4; ++f) {
      ushort4 o;
      o.x = f2b(acc[f][0]); o.y = f2b(acc[f][1]);
      o.z = f2b(acc[f][2]); o.w = f2b(acc[f][3]);
      *(ushort4*)&Cb[(long)(cn + f * 16 + lane15) * ldc + orow] = o;
    }
  }
}

// ---------------- headed K=64 MFMA pair-dot (rhs / qk / qw), frags direct from global ----------------
#define PD_RHS 0
#define PD_QK  1
#define PD_QW  2
__global__ __launch_bounds__(256) void mfma_pd64_kernel(
    const ushort* __restrict__ A, long a_hs, int a_hmode, int lda,
    const ushort* __restrict__ B, long b_hs, int b_hmode, int ldb,
    void* __restrict__ C, long c_hs, int ldc,
    const float* __restrict__ beta, int mode, int head0)
{
  int hg = blockIdx.z, h = head0 + hg;
  int rm = blockIdx.y * 64, cn = blockIdx.x * 64;
  int tid = threadIdx.x, w = tid >> 6, l = tid & 63;
  int quad = l >> 4, lane15 = l & 15;

  if (cn > rm) {
    if (mode == PD_RHS) {
      float* Cf = (float*)C + (long)hg * c_hs;
      #pragma unroll
      for (int i = 0; i < 16; ++i) {
        int e = tid + i * 256;
        int r = e >> 6, c = e & 63;
        Cf[(long)(rm + r) * ldc + cn + c] = 0.f;
      }
    }
    return;
  }
  const ushort* Ah = A + (a_hmode == 0 ? (long)h * a_hs : (long)(h >> 1) * 64);
  const ushort* Bh = B + (b_hmode == 0 ? (long)h * b_hs : (long)(h >> 1) * 64);
  f32x4 acc[4] = {};
  #pragma unroll
  for (int s = 0; s < 2; ++s) {
    bf16x8 af = *(const bf16x8*)&Ah[(long)(rm + w * 16 + lane15) * lda + s * 32 + quad * 8];
    #pragma unroll
    for (int f = 0; f < 4; ++f) {
      bf16x8 bf = *(const bf16x8*)&Bh[(long)(cn + f * 16 + lane15) * ldb + s * 32 + quad * 8];
      acc[f] = MFMA16(af, bf, acc[f]);
    }
  }
  int orow = rm + w * 16 + quad * 4;
  if (mode == PD_RHS) {
    float* Cf = (float*)C + (long)hg * c_hs;
    const float* bet = beta + (long)h * TTD;
    #pragma unroll
    for (int f = 0; f < 4; ++f)
      #pragma unroll
      for (int r = 0; r < 4; ++r) {
        int rr = orow + r, cc = cn + f * 16 + lane15;
        Cf[(long)rr * ldc + cc] = (rr > cc) ? bet[rr] * acc[f][r] : 0.f;
      }
  } else if (mode == PD_QK) {
    float* Cf = (float*)C + (long)hg * c_hs;
    #pragma unroll
    for (int f = 0; f < 4; ++f)
      #pragma unroll
      for (int r = 0; r < 4; ++r)
        Cf[(long)(orow + r) * ldc + cn + f * 16 + lane15] = acc[f][r];
  } else {
    ushort* Cb = (ushort*)C + (long)hg * c_hs;
    #pragma unroll
    for (int f = 0; f < 4; ++f)
      #pragma unroll
      for (int r = 0; r < 4; ++r) {
        int rr = orow + r, cc = cn + f * 16 + lane15;
        Cb[(long)rr * ldc + cc] = (rr >= cc) ? f2b(acc[f][r]) : (ushort)0;
      }
  }
}

// ---------------- fused panel+apply trailing update (MFMA, two back-to-back 64^3) ----------------
// Pt[j][d] = sum_s Bm[s][j]*wh[s][d]  (s in panel [r0,r0+64));  then
// Bm[r][c] -= beta[r] * sum_d wh[r][d]*Pt[c][d]   for r in row-tile, c in col-tile.
__global__ __launch_bounds__(256) void mfma_apply_kernel(
    float* __restrict__ Bm, const ushort* __restrict__ whb,
    const float* __restrict__ beta, int r0, int head0)
{
  int hg = blockIdx.z, h = head0 + hg;
  int cn = blockIdx.x * 64;
  int rm = r0 + 64 + blockIdx.y * 64;
  float* Bh = Bm + (long)hg * TTD * TTD;
  const ushort* wh_h = whb + (long)h * TTD * HDIM;
  const float* bet = beta + (long)h * TTD;

  __shared__ ushort BT[64 * 64];  // [j][s]
  __shared__ ushort WT[64 * 64];  // [d][s]
  __shared__ ushort PL[64 * 64];  // [j][d]
  int tid = threadIdx.x, w = tid >> 6, l = tid & 63;
  int quad = l >> 4, lane15 = l & 15;

  int sr = tid >> 3, jc = (tid & 7) * 8;
  #pragma unroll
  for (int it = 0; it < 2; ++it) {
    int s = it * 32 + sr;
    const float* bp = &Bh[(long)(r0 + s) * TTD + cn + jc];
    float4 f0 = *(const float4*)bp;
    float4 f1 = *(const float4*)(bp + 4);
    BT[(jc + 0) * 64 + s] = f2b(f0.x); BT[(jc + 1) * 64 + s] = f2b(f0.y);
    BT[(jc + 2) * 64 + s] = f2b(f0.z); BT[(jc + 3) * 64 + s] = f2b(f0.w);
    BT[(jc + 4) * 64 + s] = f2b(f1.x); BT[(jc + 5) * 64 + s] = f2b(f1.y);
    BT[(jc + 6) * 64 + s] = f2b(f1.z); BT[(jc + 7) * 64 + s] = f2b(f1.w);
    uint4 t = *(const uint4*)&wh_h[(long)(r0 + s) * HDIM + jc];
    const ushort* tu = (const ushort*)&t;
    #pragma unroll
    for (int i = 0; i < 8; ++i) WT[(jc + i) * 64 + s] = tu[i];
  }
  __syncthreads();

  f32x4 p1[4] = {};
  #pragma unroll
  for (int s2 = 0; s2 < 2; ++s2) {
    bf16x8 af = *(const bf16x8*)&BT[(w * 16 + lane15) * 64 + s2 * 32 + quad * 8];
    #pragma unroll
    for (int f = 0; f < 4; ++f) {
      bf16x8 bf = *(const bf16x8*)&WT[(f * 16 + lane15) * 64 + s2 * 32 + quad * 8];
      p1[f] = MFMA16(af, bf, p1[f]);
    }
  }
  #pragma unroll
  for (int f = 0; f < 4; ++f)
    #pragma unroll
    for (int r = 0; r < 4; ++r)
      PL[(w * 16 + quad * 4 + r) * 64 + f * 16 + lane15] = f2b(p1[f][r]);
  __syncthreads();

  f32x4 a2[4] = {};
  #pragma unroll
  for (int s2 = 0; s2 < 2; ++s2) {
    bf16x8 af = *(const bf16x8*)&wh_h[(long)(rm + w * 16 + lane15) * HDIM + s2 * 32 + quad * 8];
    #pragma unroll
    for (int f = 0; f < 4; ++f) {
      bf16x8 bf = *(const bf16x8*)&PL[(f * 16 + lane15) * 64 + s2 * 32 + quad * 8];
      a2[f] = MFMA16(af, bf, a2[f]);
    }
  }
  #pragma unroll
  for (int f = 0; f < 4; ++f)
    #pragma unroll
    for (int r = 0; r < 4; ++r) {
      int rr = rm + w * 16 + quad * 4 + r;
      int cc = cn + f * 16 + lane15;
      Bh[(long)rr * TTD + cc] -= bet[rr] * a2[f][r];
    }
}

// ---------------- logits -= qw @ Bmat (triangular K-range; Bmat transposed+converted via LDS) --------
__global__ __launch_bounds__(256) void mfma_qwb_kernel(
    const ushort* __restrict__ qwb, const float* __restrict__ Bm,
    float* __restrict__ lg)
{
  int hg = blockIdx.z;
  int rm = blockIdx.y * 64, cn = blockIdx.x * 64;
  if (cn > rm) return;
  const ushort* Ah = qwb + (long)hg * TTD * TTD;
  const float* Bh = Bm + (long)hg * TTD * TTD;
  float* Ch = lg + (long)hg * TTD * TTD;

  __shared__ ushort BT[64 * 32];  // [j][t]
  int tid = threadIdx.x, w = tid >> 6, l = tid & 63;
  int quad = l >> 4, lane15 = l & 15;
  int sr = tid >> 3, jc = (tid & 7) * 8;
  f32x4 acc[4] = {};
  for (int k0 = cn; k0 < rm + 64; k0 += 32) {
    const float* bp = &Bh[(long)(k0 + sr) * TTD + cn + jc];
    float4 f0 = *(const float4*)bp;
    float4 f1 = *(const float4*)(bp + 4);
    BT[(jc + 0) * 32 + sr] = f2b(f0.x); BT[(jc + 1) * 32 + sr] = f2b(f0.y);
    BT[(jc + 2) * 32 + sr] = f2b(f0.z); BT[(jc + 3) * 32 + sr] = f2b(f0.w);
    BT[(jc + 4) * 32 + sr] = f2b(f1.x); BT[(jc + 5) * 32 + sr] = f2b(f1.y);
    BT[(jc + 6) * 32 + sr] = f2b(f1.z); BT[(jc + 7) * 32 + sr] = f2b(f1.w);
    __syncthreads();
    bf16x8 af = *(const bf16x8*)&Ah[(long)(rm + w * 16 + lane15) * TTD + k0 + quad * 8];
    #pragma unroll
    for (int f = 0; f < 4; ++f) {
      bf16x8 bf = *(const bf16x8*)&BT[(f * 16 + lane15) * 32 + quad * 8];
      acc[f] = MFMA16(af, bf, acc[f]);
    }
    __syncthreads();
  }
  #pragma unroll
  for (int f = 0; f < 4; ++f)
    #pragma unroll
    for (int r = 0; r < 4; ++r)
      Ch[(long)(rm + w * 16 + quad * 4 + r) * TTD + cn + f * 16 + lane15] -= acc[f][r];
}

// ---------------- o = p @ v  (p fp32 converted in-register; vT bf16 direct frags) ----------------
__global__ __launch_bounds__(256) void mfma_pv_kernel(
    const float* __restrict__ lg, const ushort* __restrict__ vTb,
    ushort* __restrict__ oall, int head0)
{
  int hg = blockIdx.z, h = head0 + hg;
  int rm = blockIdx.y * 64;
  const float* Ph = lg + (long)hg * TTD * TTD;
  const ushort* Vh = vTb + (long)(h >> 1) * 64 * TTD;
  int tid = threadIdx.x, w = tid >> 6, l = tid & 63;
  int quad = l >> 4, lane15 = l & 15;
  f32x4 acc[4] = {};
  for (int k0 = 0; k0 < rm + 64; k0 += 32) {
    const float* pp = &Ph[(long)(rm + w * 16 + lane15) * TTD + k0 + quad * 8];
    float4 f0 = *(const float4*)pp;
    float4 f1 = *(const float4*)(pp + 4);
    union { ushort u[8]; bf16x8 v; } cv;
    cv.u[0] = f2b(f0.x); cv.u[1] = f2b(f0.y); cv.u[2] = f2b(f0.z); cv.u[3] = f2b(f0.w);
    cv.u[4] = f2b(f1.x); cv.u[5] = f2b(f1.y); cv.u[6] = f2b(f1.z); cv.u[7] = f2b(f1.w);
    #pragma unroll
    for (int f = 0; f < 4; ++f) {
      bf16x8 bf = *(const bf16x8*)&Vh[(long)(f * 16 + lane15) * TTD + k0 + quad * 8];
      acc[f] = MFMA16(cv.v, bf, acc[f]);
    }
  }
  #pragma unroll
  for (int f = 0; f < 4; ++f)
    #pragma unroll
    for (int r = 0; r < 4; ++r)
      oall[(long)(rm + w * 16 + quad * 4 + r) * 2048 + h * 64 + f * 16 + lane15] = f2b(acc[f][r]);
}

// ---------------- diagonal-block forward substitution (fp32, unchanged) ----------------
__global__ __launch_bounds__(256) void diag_solve_kernel(
    float* __restrict__ Bmat, const float* __restrict__ wh,
    const float* __restrict__ beta, int r0, int head0)
{
  int hg = blockIdx.z;
  int h = head0 + hg;
  int j = blockIdx.x * 256 + threadIdx.x;
  const float* whh = wh + (long)h * TTD * HDIM + (long)r0 * HDIM;
  const float* betah = beta + (long)h * TTD + r0;
  float* Bh = Bmat + (long)hg * TTD * TTD;

  __shared__ float whL[64][65];
  __shared__ float Lm[64][65];
  __shared__ float betaL[64];
  int tid = threadIdx.x;
  #pragma unroll
  for (int i = 0; i < 16; ++i) {
    int e = tid + i * 256;
    int r = e >> 6, c = e & 63;
    whL[r][c] = whh[(long)r * HDIM + c];
  }
  if (tid < 64) betaL[tid] = betah[tid];
  __syncthreads();
  #pragma unroll
  for (int i = 0; i < 16; ++i) {
    int e = tid + i * 256;
    int t = e >> 6, s = e & 63;
    if (s < t) {
      float d = 0.f;
      #pragma unroll
      for (int kk = 0; kk < 64; ++kk) d += whL[t][kk] * whL[s][kk];
      Lm[t][s] = betaL[t] * d;
    }
  }
  __syncthreads();

  float cur[64];
  #pragma unroll
  for (int t = 0; t < 64; ++t) cur[t] = Bh[(long)(r0 + t) * TTD + j];
  #pragma unroll
  for (int t = 0; t < 64; ++t) {
    float bv = cur[t];
    Bh[(long)(r0 + t) * TTD + j] = bv;
    #pragma unroll
    for (int u = t + 1; u < 64; ++u) cur[u] -= Lm[u][t] * bv;
  }
}

// ---------------- conv(K=3)+SiLU+rotate+normalize -> wh fp32 AND wh bf16 ----------------
__global__ __launch_bounds__(256) void convdir_kernel(
    const float* __restrict__ w_raw, const float* __restrict__ conv_w,
    const float* __restrict__ omega, const float* __restrict__ phi,
    float* __restrict__ wh, ushort* __restrict__ whb)
{
  int gid = blockIdx.x * 256 + threadIdx.x;
  int lane = gid & 63;
  int w = gid >> 6;
  int hr = w & 31, t = w >> 5;
  int hkv = hr >> 1, r = hr & 1;
  int cA = hkv * 256 + r * 128 + lane;
  int cB = cA + 64;
  float a = 0.f, b = 0.f;
  #pragma unroll
  for (int i = 0; i < 3; ++i) {
    int tp = t - 2 + i;
    if (tp >= 0) {
      a += w_raw[(long)tp * NOUTW + cA] * conv_w[cA * 3 + i];
      b += w_raw[(long)tp * NOUTW + cB] * conv_w[cB * 3 + i];
    }
  }
  a = a / (1.f + expf(-a));
  b = b / (1.f + expf(-b));
  float th = omega[r] * (float)t + phi[r];
  float wd = a * cosf(th) + b * sinf(th);
  float ss = wd * wd;
  #pragma unroll
  for (int o = 32; o > 0; o >>= 1) ss += __shfl_xor(ss, o, 64);
  float inv = 1.f / sqrtf(ss + 1e-6f);
  float v = wd * inv;
  long idx = ((long)hr * TTD + t) * HDIM + lane;
  wh[idx] = v;
  whb[idx] = f2b(v);
}

__global__ __launch_bounds__(256) void beta_kernel(
    const float* __restrict__ bt_lin, const float* __restrict__ bt_b,
    float* __restrict__ beta)
{
  int idx = blockIdx.x * 256 + threadIdx.x;
  int t = idx >> 5, hr = idx & 31;
  float x = bt_lin[t * 32 + hr] + bt_b[hr];
  beta[(long)hr * TTD + t] = 2.f / (1.f + expf(-x));
}

__global__ __launch_bounds__(256) void softmax_kernel(float* __restrict__ lg)
{
  int hg = blockIdx.z;
  int i = blockIdx.x;
  float* row = lg + (long)hg * TTD * TTD + (long)i * TTD;
  int n = i + 1;
  int tid = threadIdx.x;
  __shared__ float red1[4], red2[4];

  float mx = -1e30f;
  for (int j = tid; j < n; j += 256) mx = fmaxf(mx, row[j] * PSCALE);
  #pragma unroll
  for (int o = 32; o > 0; o >>= 1) mx = fmaxf(mx, __shfl_xor(mx, o, 64));
  if ((tid & 63) == 0) red1[tid >> 6] = mx;
  __syncthreads();
  mx = fmaxf(fmaxf(red1[0], red1[1]), fmaxf(red1[2], red1[3]));

  float s = 0.f;
  for (int j = tid; j < n; j += 256) s += __expf(row[j] * PSCALE - mx);
  #pragma unroll
  for (int o = 32; o > 0; o >>= 1) s += __shfl_xor(s, o, 64);
  if ((tid & 63) == 0) red2[tid >> 6] = s;
  __syncthreads();
  s = red2[0] + red2[1] + red2[2] + red2[3];
  float inv = 1.f / s;
  for (int j = tid; j < TTD; j += 256)
    row[j] = (j < n) ? __expf(row[j] * PSCALE - mx) * inv : 0.f;
}

// ---------------- host ----------------
extern "C" void kernel_launch(void* const* d_in, const int* in_sizes, int n_in,
                              void* d_out, int out_size, void* d_ws, size_t ws_size,
                              hipStream_t stream) {
  const float* hs     = (const float*)d_in[0];
  const float* q_w    = (const float*)d_in[1];
  const float* k_w    = (const float*)d_in[2];
  const float* v_w    = (const float*)d_in[3];
  const float* w1     = (const float*)d_in[4];
  const float* w2     = (const float*)d_in[5];
  const float* conv_w = (const float*)d_in[6];
  const float* bt_w   = (const float*)d_in[7];
  const float* bt_b   = (const float*)d_in[8];
  const float* o_w    = (const float*)d_in[9];
  const float* omega  = (const float*)d_in[10];
  const float* phi    = (const float*)d_in[11];
  float* out = (float*)d_out;
  char* ws = (char*)d_ws;

  float*  B_g    = (float*)(ws + OFF_BG);
  float*  lg     = (float*)(ws + OFF_LG);
  float*  w_raw  = (float*)(ws + OFF_WRAW);
  float*  wh     = (float*)(ws + OFF_WH);
  float*  bt_lin = (float*)(ws + OFF_BTL);
  float*  w_low  = (float*)(ws + OFF_WLOW);
  float*  beta   = (float*)(ws + OFF_BETA);
  ushort* hs_b   = (ushort*)(ws + OFF_HSB);
  ushort* qw_wb  = (ushort*)(ws + OFF_QWW);
  ushort* kw_wb  = (ushort*)(ws + OFF_KWW);
  ushort* vw_wb  = (ushort*)(ws + OFF_VWW);
  ushort* w2_b   = (ushort*)(ws + OFF_W2B);
  ushort* ow_b   = (ushort*)(ws + OFF_OWB);
  ushort* q_b    = (ushort*)(ws + OFF_QB);
  ushort* k_b    = (ushort*)(ws + OFF_KB);
  ushort* vT_b   = (ushort*)(ws + OFF_VTB);
  ushort* wlow_b = (ushort*)(ws + OFF_WLOWB);
  ushort* wh_b   = (ushort*)(ws + OFF_WHB);
  ushort* qw_b   = (ushort*)(ws + OFF_QWBUF);
  ushort* o_all  = (ushort*)(ws + OFF_OALL);

  const long TTl = (long)TTD * TTD;

  // converts
  cvt_kernel<<<dim3(1024), 256, 0, stream>>>(hs,  hs_b,  (long)TTD * DDM);
  cvt_kernel<<<dim3(1024), 256, 0, stream>>>(q_w, qw_wb, (long)DDM * DDM);
  cvt_kernel<<<dim3(1024), 256, 0, stream>>>(k_w, kw_wb, (long)DDM * DDM);
  cvt_kernel<<<dim3(1024), 256, 0, stream>>>(v_w, vw_wb, (long)DDM * DDM);
  cvt_kernel<<<dim3(128),  256, 0, stream>>>(w2,  w2_b,  (long)NOUTW * 32);
  cvt_kernel<<<dim3(2048), 256, 0, stream>>>(o_w, ow_b,  (long)DDM * 2048);

  // tiny fp32 GEMMs (N=32)
  gemm_nt_kernel<<<dim3(1, 16), 256, 0, stream>>>(hs, DDM, bt_w, DDM, bt_lin, 32, 32, DDM);
  gemm_nt_kernel<<<dim3(1, 16), 256, 0, stream>>>(hs, DDM, w1,   DDM, w_low,  32, 32, DDM);
  cvt_kernel<<<dim3(32), 256, 0, stream>>>(w_low, wlow_b, (long)TTD * 32);

  // MFMA projections
  mfma_nt_kernel<<<dim3(16, 16), 256, 0, stream>>>(hs_b, DDM, qw_wb, DDM, q_b,  DDM, DDM, ONT_B16);
  mfma_nt_kernel<<<dim3(16, 16), 256, 0, stream>>>(hs_b, DDM, kw_wb, DDM, k_b,  DDM, DDM, ONT_B16);
  mfma_nt_kernel<<<dim3(16, 16), 256, 0, stream>>>(hs_b, DDM, vw_wb, DDM, vT_b, DDM, DDM, ONT_B16T);
  mfma_nt_kernel<<<dim3(64, 16), 256, 0, stream>>>(wlow_b, 32, w2_b, 32, w_raw, NOUTW, 32, ONT_F32);

  convdir_kernel<<<dim3(8192), 256, 0, stream>>>(w_raw, conv_w, omega, phi, wh, wh_b);
  beta_kernel<<<dim3(128), 256, 0, stream>>>(bt_lin, bt_b, beta);

  for (int g = 0; g < NHR / NG; ++g) {
    int head0 = g * NG;
    // rhs: B_g[t][j] = (t>j) ? beta[t]*dot(wh_t, k_j) : 0
    mfma_pd64_kernel<<<dim3(16, 16, NG), 256, 0, stream>>>(
        wh_b, (long)TTD * HDIM, 0, HDIM, k_b, 0, 1, DDM,
        B_g, TTl, TTD, beta, PD_RHS, head0);
    // blocked forward substitution with fused panel+apply
    for (int kb = 0; kb < 16; ++kb) {
      int r0 = kb * 64;
      diag_solve_kernel<<<dim3((r0 + 64 + 255) / 256, 1, NG), 256, 0, stream>>>(
          B_g, wh, beta, r0, head0);
      if (kb < 15) {
        mfma_apply_kernel<<<dim3(kb + 1, 15 - kb, NG), 256, 0, stream>>>(
            B_g, wh_b, beta, r0, head0);
      }
    }
    // logits = qk (lower tiles only)
    mfma_pd64_kernel<<<dim3(16, 16, NG), 256, 0, stream>>>(
        q_b, 0, 1, DDM, k_b, 0, 1, DDM,
        lg, TTl, TTD, nullptr, PD_QK, head0);
    // qw (incl mask) -> bf16
    mfma_pd64_kernel<<<dim3(16, 16, NG), 256, 0, stream>>>(
        q_b, 0, 1, DDM, wh_b, (long)TTD * HDIM, 0, HDIM,
        qw_b, TTl, TTD, nullptr, PD_QW, head0);
    // logits -= qw @ Bmat
    mfma_qwb_kernel<<<dim3(16, 16, NG), 256, 0, stream>>>(qw_b, B_g, lg);
    softmax_kernel<<<dim3(TTD, 1, NG), 256, 0, stream>>>(lg);
    // o = p @ v
    mfma_pv_kernel<<<dim3(1, 16, NG), 256, 0, stream>>>(lg, vT_b, o_all, head0);
  }

  // final: out = o_all @ o_w^T
  mfma_nt_kernel<<<dim3(16, 16), 256, 0, stream>>>(o_all, 2048, ow_b, 2048, out, DDM, 2048, ONT_F32);
  (void)in_sizes; (void)n_in; (void)out_size; (void)ws_size; (void)conv_w;
}

// Round 3
// 1279.744 us; speedup vs baseline: 5.8718x; 2.6446x over previous
//
#include <hip/hip_runtime.h>
#include <math.h>

// ---------------- problem constants ----------------
#define TTD 1024
#define DDM 1024
#define NHR 32
#define HDIM 64
#define NOUTW 4096
#define PSCALE 0.125f
#define NG 8

typedef __attribute__((ext_vector_type(8))) __bf16 bf16x8;
typedef __attribute__((ext_vector_type(4))) float f32x4;
#define MFMA16(a,b,c) __builtin_amdgcn_mfma_f32_16x16x32_bf16(a,b,c,0,0,0)

__device__ __forceinline__ ushort f2b(float f) {
  unsigned u = __builtin_bit_cast(unsigned, f);
  return (ushort)((u + 0x7fffu + ((u >> 16) & 1u)) >> 16);
}

__device__ __forceinline__ void gload_lds16(const ushort* g, ushort* l) {
  __builtin_amdgcn_global_load_lds(
      (const __attribute__((address_space(1))) unsigned*)g,
      (__attribute__((address_space(3))) unsigned*)l, 16, 0, 0);
}

// ---------------- workspace layout (bytes); end = 145,424,384 (138.7 MiB) ----------------
#define OFF_XB    0L           // X (Bmat) bf16 [32][j][t] : 64 MiB
#define OFF_LG    67108864L    // logits fp32 [8][i][j] : 32 MiB
#define OFF_WRAW  67108864L    // w_raw fp32 1024x4096 (aliases LG; consumed before LG written)
#define OFF_QP    100663296L   // qw bf16 then p bf16 [8][i][t] : 16 MiB
#define OFF_HSB   117440512L
#define OFF_QWW   119537664L
#define OFF_KWW   121634816L
#define OFF_VWW   123731968L
#define OFF_W2B   125829120L
#define OFF_OWB   126091264L
#define OFF_QB    130285568L
#define OFF_KB    132382720L
#define OFF_VTB   134479872L
#define OFF_WLOWB 136577024L
#define OFF_WHB   136642560L
#define OFF_BETA  140836864L
#define OFF_BTL   140967936L
#define OFF_BW64  141099008L
#define OFF_OALL  141230080L

// ---------------- fp32 -> bf16 convert ----------------
__global__ __launch_bounds__(256) void cvt_kernel(const float* __restrict__ x,
                                                  ushort* __restrict__ y, long n) {
  long i = ((long)blockIdx.x * 256 + threadIdx.x) * 4;
  if (i >= n) return;
  float4 f = *(const float4*)(x + i);
  ushort4 o;
  o.x = f2b(f.x); o.y = f2b(f.y); o.z = f2b(f.z); o.w = f2b(f.w);
  *(ushort4*)(y + i) = o;
}

// ---------------- MFMA NT GEMM, 64x64 tile ----------------
#define ONT_F32  0
#define ONT_B16  1
#define ONT_B16T 2
__global__ __launch_bounds__(256) void mfma_nt_kernel(
    const ushort* __restrict__ A, int lda,
    const ushort* __restrict__ B, int ldb,
    void* __restrict__ C, int ldc, int K, int outmode)
{
  __shared__ ushort As[64 * 32];
  __shared__ ushort Bs[64 * 32];
  int tid = threadIdx.x, w = tid >> 6, l = tid & 63;
  int quad = l >> 4, lane15 = l & 15;
  int rm = blockIdx.y * 64, cn = blockIdx.x * 64;
  int row = tid >> 2, ch = (tid & 3) * 8;
  f32x4 acc[4] = {};
  for (int k0 = 0; k0 < K; k0 += 32) {
    gload_lds16(A + (long)(rm + row) * lda + k0 + ch, &As[tid * 8]);
    gload_lds16(B + (long)(cn + row) * ldb + k0 + ch, &Bs[tid * 8]);
    __syncthreads();
    bf16x8 af = *(const bf16x8*)&As[(w * 16 + lane15) * 32 + quad * 8];
    #pragma unroll
    for (int f = 0; f < 4; ++f) {
      bf16x8 bf = *(const bf16x8*)&Bs[(f * 16 + lane15) * 32 + quad * 8];
      acc[f] = MFMA16(af, bf, acc[f]);
    }
    __syncthreads();
  }
  int orow = rm + w * 16 + quad * 4;
  if (outmode == ONT_F32) {
    float* Cf = (float*)C;
    #pragma unroll
    for (int f = 0; f < 4; ++f)
      #pragma unroll
      for (int r = 0; r < 4; ++r)
        Cf[(long)(orow + r) * ldc + cn + f * 16 + lane15] = acc[f][r];
  } else if (outmode == ONT_B16) {
    ushort* Cb = (ushort*)C;
    #pragma unroll
    for (int f = 0; f < 4; ++f)
      #pragma unroll
      for (int r = 0; r < 4; ++r)
        Cb[(long)(orow + r) * ldc + cn + f * 16 + lane15] = f2b(acc[f][r]);
  } else {
    ushort* Cb = (ushort*)C;
    #pragma unroll
    for (int f = 0; f < 4; ++f) {
      ushort4 o;
      o.x = f2b(acc[f][0]); o.y = f2b(acc[f][1]);
      o.z = f2b(acc[f][2]); o.w = f2b(acc[f][3]);
      *(ushort4*)&Cb[(long)(cn + f * 16 + lane15) * ldc + orow] = o;
    }
  }
}

// ---------------- fused small projections: bt_lin (fp32) + w_low (bf16), both 1024x32 ----------------
__global__ __launch_bounds__(256) void smallproj_kernel(
    const ushort* __restrict__ hsb, const ushort* __restrict__ bw,
    float* __restrict__ bt_lin, ushort* __restrict__ wlowb)
{
  int rm = blockIdx.x * 64;
  int tid = threadIdx.x, w = tid >> 6, l = tid & 63;
  int quad = l >> 4, lane15 = l & 15;
  f32x4 acc[4] = {};
  for (int k0 = 0; k0 < 1024; k0 += 32) {
    bf16x8 af = *(const bf16x8*)&hsb[(long)(rm + w * 16 + lane15) * 1024 + k0 + quad * 8];
    #pragma unroll
    for (int f = 0; f < 4; ++f) {
      bf16x8 bf = *(const bf16x8*)&bw[(long)(f * 16 + lane15) * 1024 + k0 + quad * 8];
      acc[f] = MFMA16(af, bf, acc[f]);
    }
  }
  int orow = rm + w * 16 + quad * 4;
  #pragma unroll
  for (int f = 0; f < 2; ++f)
    #pragma unroll
    for (int r = 0; r < 4; ++r)
      bt_lin[(long)(orow + r) * 32 + f * 16 + lane15] = acc[f][r];
  #pragma unroll
  for (int f = 2; f < 4; ++f)
    #pragma unroll
    for (int r = 0; r < 4; ++r)
      wlowb[(long)(orow + r) * 32 + (f - 2) * 16 + lane15] = f2b(acc[f][r]);
}

// ---------------- headed K=64 MFMA pair-dot (qk / qw), frags direct from global ----------------
#define PD_QK  1
#define PD_QW  2
__global__ __launch_bounds__(256) void mfma_pd64_kernel(
    const ushort* __restrict__ A, long a_hs, int a_hmode, int lda,
    const ushort* __restrict__ B, long b_hs, int b_hmode, int ldb,
    void* __restrict__ C, long c_hs, int ldc, int mode, int head0)
{
  int hg = blockIdx.z, h = head0 + hg;
  int rm = blockIdx.y * 64, cn = blockIdx.x * 64;
  if (cn > rm) return;
  int tid = threadIdx.x, w = tid >> 6, l = tid & 63;
  int quad = l >> 4, lane15 = l & 15;
  const ushort* Ah = A + (a_hmode == 0 ? (long)h * a_hs : (long)(h >> 1) * 64);
  const ushort* Bh = B + (b_hmode == 0 ? (long)h * b_hs : (long)(h >> 1) * 64);
  f32x4 acc[4] = {};
  #pragma unroll
  for (int s = 0; s < 2; ++s) {
    bf16x8 af = *(const bf16x8*)&Ah[(long)(rm + w * 16 + lane15) * lda + s * 32 + quad * 8];
    #pragma unroll
    for (int f = 0; f < 4; ++f) {
      bf16x8 bf = *(const bf16x8*)&Bh[(long)(cn + f * 16 + lane15) * ldb + s * 32 + quad * 8];
      acc[f] = MFMA16(af, bf, acc[f]);
    }
  }
  int orow = rm + w * 16 + quad * 4;
  if (mode == PD_QK) {
    float* Cf = (float*)C + (long)hg * c_hs;
    #pragma unroll
    for (int f = 0; f < 4; ++f)
      #pragma unroll
      for (int r = 0; r < 4; ++r)
        Cf[(long)(orow + r) * ldc + cn + f * 16 + lane15] = acc[f][r];
  } else {
    ushort* Cb = (ushort*)C + (long)hg * c_hs;
    #pragma unroll
    for (int f = 0; f < 4; ++f)
      #pragma unroll
      for (int r = 0; r < 4; ++r) {
        int rr = orow + r, cc = cn + f * 16 + lane15;
        Cb[(long)rr * ldc + cc] = (rr >= cc) ? f2b(acc[f][r]) : (ushort)0;
      }
  }
}

// ---------------- ONE-LAUNCH triangular solve via low-rank recurrence ----------------
// Per block: head h, column slab [j0,j0+64). State S[d][c] = sum_{s<t0} wh[s][d]*X[s][c] (fp32 regs).
// Per 64-row chunk: V = beta.*(strict_mask(wh.k^T) - wh.S); local Lm = beta.*(wh.wh^T);
// wavefront substitution; X written bf16 transposed [j][t]; S += wh^T.X.
__global__ __launch_bounds__(256) void solve_kernel(
    const ushort* __restrict__ whb,   // [h][t][d]
    const ushort* __restrict__ kb,    // [t][D]
    const float* __restrict__ beta,   // [h][t]
    ushort* __restrict__ Xb)          // [h][j][t]
{
  int h = blockIdx.y;
  int j0 = blockIdx.x * 64;
  const ushort* wh_h = whb + (long)h * TTD * HDIM;
  const ushort* k_h  = kb + (long)(h >> 1) * 64;
  const float* bet = beta + (long)h * TTD;
  ushort* X_h = Xb + (long)h * TTD * TTD;

  __shared__ ushort WT[64 * 64];   // wh^T chunk [d][t]
  __shared__ ushort nS[64 * 64];   // -S bf16 [c][d]
  __shared__ float  Lm[64][65];
  __shared__ float  Vf[64][65];    // V then X fp32 [t][c]
  __shared__ ushort Xc[64 * 64];   // X bf16 [c][t]

  int tid = threadIdx.x, w = tid >> 6, l = tid & 63;
  int quad = l >> 4, lane15 = l & 15;

  f32x4 S[4] = {};
  #pragma unroll
  for (int i = 0; i < 8; ++i) ((unsigned*)nS)[tid + i * 256] = 0;
  int kb_start = j0 >> 6;

  for (int kbi = kb_start; kbi < 16; ++kbi) {
    int t0 = kbi * 64;
    const ushort* whc = wh_h + (long)t0 * HDIM;
    __syncthreads();  // B0: WT/Vf/Lm WAR vs prev iter; nS writes visible

    // stage WT[d][t]
    {
      int d0 = (tid & 7) * 8;
      #pragma unroll
      for (int it = 0; it < 2; ++it) {
        int t = it * 32 + (tid >> 3);
        uint4 pk = *(const uint4*)&whc[(long)t * HDIM + d0];
        const ushort* pu = (const ushort*)&pk;
        #pragma unroll
        for (int i = 0; i < 8; ++i) WT[(d0 + i) * 64 + t] = pu[i];
      }
    }
    // V = wh.k^T + wh.(-S);  G = wh.wh^T
    f32x4 vacc[4] = {};
    f32x4 gacc[4] = {};
    #pragma unroll
    for (int s = 0; s < 2; ++s) {
      bf16x8 af = *(const bf16x8*)&whc[(long)(w * 16 + lane15) * HDIM + s * 32 + quad * 8];
      #pragma unroll
      for (int f = 0; f < 4; ++f) {
        bf16x8 bk = *(const bf16x8*)&k_h[(long)(j0 + f * 16 + lane15) * DDM + s * 32 + quad * 8];
        vacc[f] = MFMA16(af, bk, vacc[f]);
        bf16x8 bs = *(const bf16x8*)&nS[(f * 16 + lane15) * 64 + s * 32 + quad * 8];
        vacc[f] = MFMA16(af, bs, vacc[f]);
        bf16x8 bw2 = *(const bf16x8*)&whc[(long)(f * 16 + lane15) * HDIM + s * 32 + quad * 8];
        gacc[f] = MFMA16(af, bw2, gacc[f]);
      }
    }
    // write V (beta, strict mask on diagonal chunk) and Lm
    {
      int trow = w * 16 + quad * 4;
      bool diag = (kbi == kb_start);
      #pragma unroll
      for (int f = 0; f < 4; ++f)
        #pragma unroll
        for (int r = 0; r < 4; ++r) {
          int t = trow + r, c = f * 16 + lane15;
          float bv = bet[t0 + t];
          float vv = bv * vacc[f][r];
          if (diag && t <= c) vv = 0.f;
          Vf[t][c] = vv;
          Lm[t][c] = bv * gacc[f][r];
        }
    }
    __syncthreads();  // B2

    // wavefront substitution: wave p owns rows [16p,16p+16), lane = column
    {
      float cur[16];
      #pragma unroll
      for (int i = 0; i < 16; ++i) cur[i] = Vf[w * 16 + i][l];
      for (int sb = 0; sb < 4; ++sb) {
        if (w == sb) {
          float xloc[16];
          #pragma unroll
          for (int i = 0; i < 16; ++i) {
            float bv = cur[i];
            #pragma unroll
            for (int j2 = 0; j2 < 16; ++j2)
              if (j2 < i) bv -= Lm[sb * 16 + i][sb * 16 + j2] * xloc[j2];
            xloc[i] = bv;
            Vf[sb * 16 + i][l] = bv;
          }
        }
        __syncthreads();
        if (w > sb) {
          float xp[16];
          #pragma unroll
          for (int t = 0; t < 16; ++t) xp[t] = Vf[sb * 16 + t][l];
          #pragma unroll
          for (int i = 0; i < 16; ++i) {
            float s2 = cur[i];
            #pragma unroll
            for (int t = 0; t < 16; ++t) s2 -= Lm[w * 16 + i][sb * 16 + t] * xp[t];
            cur[i] = s2;
          }
        }
      }
    }
    // convert X -> Xc [c][t] bf16
    {
      int c = tid >> 2, ts = (tid & 3) * 16;
      #pragma unroll
      for (int i = 0; i < 16; ++i) Xc[c * 64 + ts + i] = f2b(Vf[ts + i][c]);
    }
    __syncthreads();  // B3: Xc visible

    // global write X^T and S update
    {
      int c = tid >> 2, ts = (tid & 3) * 16;
      uint4 a = *(const uint4*)&Xc[c * 64 + ts];
      uint4 b = *(const uint4*)&Xc[c * 64 + ts + 8];
      *(uint4*)&X_h[(long)(j0 + c) * TTD + t0 + ts] = a;
      *(uint4*)&X_h[(long)(j0 + c) * TTD + t0 + ts + 8] = b;
    }
    #pragma unroll
    for (int s = 0; s < 2; ++s) {
      bf16x8 af = *(const bf16x8*)&WT[(w * 16 + lane15) * 64 + s * 32 + quad * 8];
      #pragma unroll
      for (int f = 0; f < 4; ++f) {
        bf16x8 bf = *(const bf16x8*)&Xc[(f * 16 + lane15) * 64 + s * 32 + quad * 8];
        S[f] = MFMA16(af, bf, S[f]);
      }
    }
    // refresh nS = -S bf16 [c][d]
    {
      int d0 = w * 16 + quad * 4;
      #pragma unroll
      for (int f = 0; f < 4; ++f)
        #pragma unroll
        for (int r = 0; r < 4; ++r)
          nS[(f * 16 + lane15) * 64 + d0 + r] = f2b(-S[f][r]);
    }
  }
}

// ---------------- logits -= qw @ X (direct bf16 fragments, triangular K-range) ----------------
__global__ __launch_bounds__(256) void mfma_qwb_kernel(
    const ushort* __restrict__ qwb, const ushort* __restrict__ Xb,
    float* __restrict__ lg, int head0)
{
  int hg = blockIdx.z;
  int rm = blockIdx.y * 64, cn = blockIdx.x * 64;
  if (cn > rm) return;
  const ushort* Ah = qwb + (long)hg * TTD * TTD;
  const ushort* Bh = Xb + (long)(head0 + hg) * TTD * TTD;
  float* Ch = lg + (long)hg * TTD * TTD;
  int tid = threadIdx.x, w = tid >> 6, l = tid & 63;
  int quad = l >> 4, lane15 = l & 15;
  f32x4 acc[4] = {};
  for (int k0 = cn; k0 < rm + 64; k0 += 32) {
    bf16x8 af = *(const bf16x8*)&Ah[(long)(rm + w * 16 + lane15) * TTD + k0 + quad * 8];
    #pragma unroll
    for (int f = 0; f < 4; ++f) {
      bf16x8 bf = *(const bf16x8*)&Bh[(long)(cn + f * 16 + lane15) * TTD + k0 + quad * 8];
      acc[f] = MFMA16(af, bf, acc[f]);
    }
  }
  #pragma unroll
  for (int f = 0; f < 4; ++f)
    #pragma unroll
    for (int r = 0; r < 4; ++r)
      Ch[(long)(rm + w * 16 + quad * 4 + r) * TTD + cn + f * 16 + lane15] -= acc[f][r];
}

// ---------------- o = p @ v (direct bf16 fragments) ----------------
__global__ __launch_bounds__(256) void mfma_pv_kernel(
    const ushort* __restrict__ pb, const ushort* __restrict__ vTb,
    ushort* __restrict__ oall, int head0)
{
  int hg = blockIdx.z, h = head0 + hg;
  int rm = blockIdx.y * 64;
  const ushort* Ph = pb + (long)hg * TTD * TTD;
  const ushort* Vh = vTb + (long)(h >> 1) * 64 * TTD;
  int tid = threadIdx.x, w = tid >> 6, l = tid & 63;
  int quad = l >> 4, lane15 = l & 15;
  f32x4 acc[4] = {};
  for (int k0 = 0; k0 < rm + 64; k0 += 32) {
    bf16x8 af = *(const bf16x8*)&Ph[(long)(rm + w * 16 + lane15) * TTD + k0 + quad * 8];
    #pragma unroll
    for (int f = 0; f < 4; ++f) {
      bf16x8 bf = *(const bf16x8*)&Vh[(long)(f * 16 + lane15) * TTD + k0 + quad * 8];
      acc[f] = MFMA16(af, bf, acc[f]);
    }
  }
  #pragma unroll
  for (int f = 0; f < 4; ++f)
    #pragma unroll
    for (int r = 0; r < 4; ++r)
      oall[(long)(rm + w * 16 + quad * 4 + r) * 2048 + h * 64 + f * 16 + lane15] = f2b(acc[f][r]);
}

// ---------------- conv(K=3)+SiLU+rotate+normalize -> wh bf16 ----------------
__global__ __launch_bounds__(256) void convdir_kernel(
    const float* __restrict__ w_raw, const float* __restrict__ conv_w,
    const float* __restrict__ omega, const float* __restrict__ phi,
    ushort* __restrict__ whb)
{
  int gid = blockIdx.x * 256 + threadIdx.x;
  int lane = gid & 63;
  int w = gid >> 6;
  int hr = w & 31, t = w >> 5;
  int hkv = hr >> 1, r = hr & 1;
  int cA = hkv * 256 + r * 128 + lane;
  int cB = cA + 64;
  float a = 0.f, b = 0.f;
  #pragma unroll
  for (int i = 0; i < 3; ++i) {
    int tp = t - 2 + i;
    if (tp >= 0) {
      a += w_raw[(long)tp * NOUTW + cA] * conv_w[cA * 3 + i];
      b += w_raw[(long)tp * NOUTW + cB] * conv_w[cB * 3 + i];
    }
  }
  a = a / (1.f + expf(-a));
  b = b / (1.f + expf(-b));
  float th = omega[r] * (float)t + phi[r];
  float wd = a * cosf(th) + b * sinf(th);
  float ss = wd * wd;
  #pragma unroll
  for (int o = 32; o > 0; o >>= 1) ss += __shfl_xor(ss, o, 64);
  float inv = 1.f / sqrtf(ss + 1e-6f);
  whb[((long)hr * TTD + t) * HDIM + lane] = f2b(wd * inv);
}

__global__ __launch_bounds__(256) void beta_kernel(
    const float* __restrict__ bt_lin, const float* __restrict__ bt_b,
    float* __restrict__ beta)
{
  int idx = blockIdx.x * 256 + threadIdx.x;
  int t = idx >> 5, hr = idx & 31;
  float x = bt_lin[t * 32 + hr] + bt_b[hr];
  beta[(long)hr * TTD + t] = 2.f / (1.f + expf(-x));
}

// ---------------- causal softmax: lg fp32 -> p bf16 ----------------
__global__ __launch_bounds__(256) void softmax_kernel(const float* __restrict__ lg,
                                                      ushort* __restrict__ pb)
{
  int hg = blockIdx.z;
  int i = blockIdx.x;
  const float* row = lg + (long)hg * TTD * TTD + (long)i * TTD;
  ushort* prow = pb + (long)hg * TTD * TTD + (long)i * TTD;
  int n = i + 1;
  int tid = threadIdx.x;
  __shared__ float red1[4], red2[4];

  float mx = -1e30f;
  for (int j = tid; j < n; j += 256) mx = fmaxf(mx, row[j] * PSCALE);
  #pragma unroll
  for (int o = 32; o > 0; o >>= 1) mx = fmaxf(mx, __shfl_xor(mx, o, 64));
  if ((tid & 63) == 0) red1[tid >> 6] = mx;
  __syncthreads();
  mx = fmaxf(fmaxf(red1[0], red1[1]), fmaxf(red1[2], red1[3]));

  float s = 0.f;
  for (int j = tid; j < n; j += 256) s += __expf(row[j] * PSCALE - mx);
  #pragma unroll
  for (int o = 32; o > 0; o >>= 1) s += __shfl_xor(s, o, 64);
  if ((tid & 63) == 0) red2[tid >> 6] = s;
  __syncthreads();
  s = red2[0] + red2[1] + red2[2] + red2[3];
  float inv = 1.f / s;
  for (int j = tid; j < TTD; j += 256)
    prow[j] = (j < n) ? f2b(__expf(row[j] * PSCALE - mx) * inv) : (ushort)0;
}

// ---------------- host ----------------
extern "C" void kernel_launch(void* const* d_in, const int* in_sizes, int n_in,
                              void* d_out, int out_size, void* d_ws, size_t ws_size,
                              hipStream_t stream) {
  const float* hs     = (const float*)d_in[0];
  const float* q_w    = (const float*)d_in[1];
  const float* k_w    = (const float*)d_in[2];
  const float* v_w    = (const float*)d_in[3];
  const float* w1     = (const float*)d_in[4];
  const float* w2     = (const float*)d_in[5];
  const float* conv_w = (const float*)d_in[6];
  const float* bt_w   = (const float*)d_in[7];
  const float* bt_b   = (const float*)d_in[8];
  const float* o_w    = (const float*)d_in[9];
  const float* omega  = (const float*)d_in[10];
  const float* phi    = (const float*)d_in[11];
  float* out = (float*)d_out;
  char* ws = (char*)d_ws;

  ushort* Xb     = (ushort*)(ws + OFF_XB);
  float*  lg     = (float*)(ws + OFF_LG);
  float*  w_raw  = (float*)(ws + OFF_WRAW);
  ushort* qp_b   = (ushort*)(ws + OFF_QP);
  ushort* hs_b   = (ushort*)(ws + OFF_HSB);
  ushort* qw_wb  = (ushort*)(ws + OFF_QWW);
  ushort* kw_wb  = (ushort*)(ws + OFF_KWW);
  ushort* vw_wb  = (ushort*)(ws + OFF_VWW);
  ushort* w2_b   = (ushort*)(ws + OFF_W2B);
  ushort* ow_b   = (ushort*)(ws + OFF_OWB);
  ushort* q_b    = (ushort*)(ws + OFF_QB);
  ushort* k_b    = (ushort*)(ws + OFF_KB);
  ushort* vT_b   = (ushort*)(ws + OFF_VTB);
  ushort* wlow_b = (ushort*)(ws + OFF_WLOWB);
  ushort* wh_b   = (ushort*)(ws + OFF_WHB);
  float*  beta   = (float*)(ws + OFF_BETA);
  float*  bt_lin = (float*)(ws + OFF_BTL);
  ushort* bw_b   = (ushort*)(ws + OFF_BW64);
  ushort* o_all  = (ushort*)(ws + OFF_OALL);

  const long TTl = (long)TTD * TTD;

  // converts
  cvt_kernel<<<dim3(1024), 256, 0, stream>>>(hs,  hs_b,  (long)TTD * DDM);
  cvt_kernel<<<dim3(1024), 256, 0, stream>>>(q_w, qw_wb, (long)DDM * DDM);
  cvt_kernel<<<dim3(1024), 256, 0, stream>>>(k_w, kw_wb, (long)DDM * DDM);
  cvt_kernel<<<dim3(1024), 256, 0, stream>>>(v_w, vw_wb, (long)DDM * DDM);
  cvt_kernel<<<dim3(128),  256, 0, stream>>>(w2,  w2_b,  (long)NOUTW * 32);
  cvt_kernel<<<dim3(2048), 256, 0, stream>>>(o_w, ow_b,  (long)DDM * 2048);
  cvt_kernel<<<dim3(32),   256, 0, stream>>>(bt_w, bw_b,            (long)32 * DDM);
  cvt_kernel<<<dim3(32),   256, 0, stream>>>(w1,   bw_b + 32 * DDM, (long)32 * DDM);

  // small projections (bt_lin fp32 + w_low bf16) + beta
  smallproj_kernel<<<dim3(16), 256, 0, stream>>>(hs_b, bw_b, bt_lin, wlow_b);
  beta_kernel<<<dim3(128), 256, 0, stream>>>(bt_lin, bt_b, beta);

  // MFMA projections
  mfma_nt_kernel<<<dim3(16, 16), 256, 0, stream>>>(hs_b, DDM, qw_wb, DDM, q_b,  DDM, DDM, ONT_B16);
  mfma_nt_kernel<<<dim3(16, 16), 256, 0, stream>>>(hs_b, DDM, kw_wb, DDM, k_b,  DDM, DDM, ONT_B16);
  mfma_nt_kernel<<<dim3(16, 16), 256, 0, stream>>>(hs_b, DDM, vw_wb, DDM, vT_b, DDM, DDM, ONT_B16T);
  mfma_nt_kernel<<<dim3(64, 16), 256, 0, stream>>>(wlow_b, 32, w2_b, 32, w_raw, NOUTW, 32, ONT_F32);

  convdir_kernel<<<dim3(8192), 256, 0, stream>>>(w_raw, conv_w, omega, phi, wh_b);

  // entire triangular solve, all 32 heads, ONE launch
  solve_kernel<<<dim3(16, 32), 256, 0, stream>>>(wh_b, k_b, beta, Xb);

  for (int g = 0; g < NHR / NG; ++g) {
    int head0 = g * NG;
    mfma_pd64_kernel<<<dim3(16, 16, NG), 256, 0, stream>>>(
        q_b, 0, 1, DDM, k_b, 0, 1, DDM, lg, TTl, TTD, PD_QK, head0);
    mfma_pd64_kernel<<<dim3(16, 16, NG), 256, 0, stream>>>(
        q_b, 0, 1, DDM, wh_b, (long)TTD * HDIM, 0, HDIM, qp_b, TTl, TTD, PD_QW, head0);
    mfma_qwb_kernel<<<dim3(16, 16, NG), 256, 0, stream>>>(qp_b, Xb, lg, head0);
    softmax_kernel<<<dim3(TTD, 1, NG), 256, 0, stream>>>(lg, qp_b);
    mfma_pv_kernel<<<dim3(1, 16, NG), 256, 0, stream>>>(qp_b, vT_b, o_all, head0);
  }

  // final: out = o_all @ o_w^T
  mfma_nt_kernel<<<dim3(16, 16), 256, 0, stream>>>(o_all, 2048, ow_b, 2048, out, DDM, 2048, ONT_F32);
  (void)in_sizes; (void)n_in; (void)out_size; (void)ws_size;
}

// Round 4
// 380.886 us; speedup vs baseline: 19.7287x; 3.3599x over previous
//
#include <hip/hip_runtime.h>
#include <math.h>

// ---------------- problem constants ----------------
#define TTD 1024
#define DDM 1024
#define HDIM 64
#define NOUTW 4096
#define PSCALE 0.125f
#define LS 72   // LDS leading stride in bf16 elems (144 B: 16B-aligned rows, spread banks)

typedef __attribute__((ext_vector_type(8))) __bf16 bf16x8;
typedef __attribute__((ext_vector_type(4))) float f32x4;
#define MFMA16(a,b,c) __builtin_amdgcn_mfma_f32_16x16x32_bf16(a,b,c,0,0,0)

__device__ __forceinline__ ushort f2b(float f) {
  unsigned u = __builtin_bit_cast(unsigned, f);
  return (ushort)((u + 0x7fffu + ((u >> 16) & 1u)) >> 16);
}

__device__ __forceinline__ void gload_lds16(const ushort* g, ushort* l) {
  __builtin_amdgcn_global_load_lds(
      (const __attribute__((address_space(1))) unsigned*)g,
      (__attribute__((address_space(3))) unsigned*)l, 16, 0, 0);
}

// ---------------- workspace layout (bytes); total = 149,291,008 (proven in R1) ----------------
#define OFF_X     0L            // X bf16 [32 h][1024 j][1024 t] : 64 MiB
#define OFF_PZ    67108864L     // PZ bf16 [32 h][15 lev][1024 j][64 d] : 60 MiB (negated prefix)
// aliases inside PZ (dead before solveB writes PZ):
#define OFF_HSB   67108864L
#define OFF_QWW   69206016L
#define OFF_KWW   71303168L
#define OFF_VWW   73400320L
#define OFF_W2B   75497472L
#define OFF_WLOWB 75759616L
#define OFF_WRAW  83886080L     // fp32 1024x4096 (16 MiB), dead after convdir
#define OFF_OWB   100663296L    // ow bf16 (4 MiB), converted AFTER flash
#define OFF_TB    130023424L    // Tbeta bf16 [32][16][64][64] : 4 MiB ; o_all aliases here after solveB
#define OFF_OALL  130023424L
#define OFF_YB    134217728L    // Yb bf16 [32][16][64][64] : 4 MiB
#define OFF_WHB   138412032L    // wh bf16 [32][1024][64] : 4 MiB
#define OFF_QB    142606336L
#define OFF_KB    144703488L
#define OFF_VTB   146800640L
#define OFF_BETA  148897792L
#define OFF_BTL   149028864L
#define OFF_BW64  149159936L

// ---------------- fp32 -> bf16 convert ----------------
__global__ __launch_bounds__(256) void cvt_kernel(const float* __restrict__ x,
                                                  ushort* __restrict__ y, long n) {
  long i = ((long)blockIdx.x * 256 + threadIdx.x) * 4;
  if (i >= n) return;
  float4 f = *(const float4*)(x + i);
  ushort4 o;
  o.x = f2b(f.x); o.y = f2b(f.y); o.z = f2b(f.z); o.w = f2b(f.w);
  *(ushort4*)(y + i) = o;
}

// ---------------- MFMA NT GEMM, 64x64 tile ----------------
#define ONT_F32  0
#define ONT_B16  1
#define ONT_B16T 2
__global__ __launch_bounds__(256) void mfma_nt_kernel(
    const ushort* __restrict__ A, int lda,
    const ushort* __restrict__ B, int ldb,
    void* __restrict__ C, int ldc, int K, int outmode)
{
  __shared__ ushort As[64 * 32];
  __shared__ ushort Bs[64 * 32];
  int tid = threadIdx.x, w = tid >> 6, l = tid & 63;
  int quad = l >> 4, lane15 = l & 15;
  int rm = blockIdx.y * 64, cn = blockIdx.x * 64;
  int row = tid >> 2, ch = (tid & 3) * 8;
  f32x4 acc[4] = {};
  for (int k0 = 0; k0 < K; k0 += 32) {
    gload_lds16(A + (long)(rm + row) * lda + k0 + ch, &As[tid * 8]);
    gload_lds16(B + (long)(cn + row) * ldb + k0 + ch, &Bs[tid * 8]);
    __syncthreads();
    bf16x8 af = *(const bf16x8*)&As[(w * 16 + lane15) * 32 + quad * 8];
    #pragma unroll
    for (int f = 0; f < 4; ++f) {
      bf16x8 bf = *(const bf16x8*)&Bs[(f * 16 + lane15) * 32 + quad * 8];
      acc[f] = MFMA16(af, bf, acc[f]);
    }
    __syncthreads();
  }
  int orow = rm + w * 16 + quad * 4;
  if (outmode == ONT_F32) {
    float* Cf = (float*)C;
    #pragma unroll
    for (int f = 0; f < 4; ++f)
      #pragma unroll
      for (int r = 0; r < 4; ++r)
        Cf[(long)(orow + r) * ldc + cn + f * 16 + lane15] = acc[f][r];
  } else if (outmode == ONT_B16) {
    ushort* Cb = (ushort*)C;
    #pragma unroll
    for (int f = 0; f < 4; ++f)
      #pragma unroll
      for (int r = 0; r < 4; ++r)
        Cb[(long)(orow + r) * ldc + cn + f * 16 + lane15] = f2b(acc[f][r]);
  } else {
    ushort* Cb = (ushort*)C;
    #pragma unroll
    for (int f = 0; f < 4; ++f) {
      ushort4 o;
      o.x = f2b(acc[f][0]); o.y = f2b(acc[f][1]);
      o.z = f2b(acc[f][2]); o.w = f2b(acc[f][3]);
      *(ushort4*)&Cb[(long)(cn + f * 16 + lane15) * ldc + orow] = o;
    }
  }
}

// ---------------- fused small projections: bt_lin (fp32) + w_low (bf16) ----------------
__global__ __launch_bounds__(256) void smallproj_kernel(
    const ushort* __restrict__ hsb, const ushort* __restrict__ bw,
    float* __restrict__ bt_lin, ushort* __restrict__ wlowb)
{
  int rm = blockIdx.x * 64;
  int tid = threadIdx.x, w = tid >> 6, l = tid & 63;
  int quad = l >> 4, lane15 = l & 15;
  f32x4 acc[4] = {};
  for (int k0 = 0; k0 < 1024; k0 += 32) {
    bf16x8 af = *(const bf16x8*)&hsb[(long)(rm + w * 16 + lane15) * 1024 + k0 + quad * 8];
    #pragma unroll
    for (int f = 0; f < 4; ++f) {
      bf16x8 bf = *(const bf16x8*)&bw[(long)(f * 16 + lane15) * 1024 + k0 + quad * 8];
      acc[f] = MFMA16(af, bf, acc[f]);
    }
  }
  int orow = rm + w * 16 + quad * 4;
  #pragma unroll
  for (int f = 0; f < 2; ++f)
    #pragma unroll
    for (int r = 0; r < 4; ++r)
      bt_lin[(long)(orow + r) * 32 + f * 16 + lane15] = acc[f][r];
  #pragma unroll
  for (int f = 2; f < 4; ++f)
    #pragma unroll
    for (int r = 0; r < 4; ++r)
      wlowb[(long)(orow + r) * 32 + (f - 2) * 16 + lane15] = f2b(acc[f][r]);
}

// ---------------- solveA: per (chunk c, head h): Tbeta = (I+Lm)^-1 diag(beta), Yb = Tbeta.wh ----------------
__global__ __launch_bounds__(256) void solveA_kernel(
    const ushort* __restrict__ whb, const float* __restrict__ beta,
    ushort* __restrict__ TB, ushort* __restrict__ YB)
{
  int c = blockIdx.x, h = blockIdx.y;
  const ushort* whc = whb + ((long)h * TTD + c * 64) * HDIM;
  const float* bet = beta + (long)h * TTD + c * 64;
  ushort* TBh = TB + ((long)h * 16 + c) * 4096;
  ushort* YBh = YB + ((long)h * 16 + c) * 4096;

  __shared__ float Lm[64][65];
  __shared__ float Vf[64][65];
  __shared__ ushort WT[64 * LS];
  __shared__ ushort Tb[64 * LS];

  int tid = threadIdx.x, w = tid >> 6, l = tid & 63;
  int quad = l >> 4, lane15 = l & 15;

  // G = wh.wh^T  (rows t, cols t')
  f32x4 g[4] = {};
  #pragma unroll
  for (int s = 0; s < 2; ++s) {
    bf16x8 af = *(const bf16x8*)&whc[(long)(w * 16 + lane15) * HDIM + s * 32 + quad * 8];
    #pragma unroll
    for (int f = 0; f < 4; ++f) {
      bf16x8 bf = *(const bf16x8*)&whc[(long)(f * 16 + lane15) * HDIM + s * 32 + quad * 8];
      g[f] = MFMA16(af, bf, g[f]);
    }
  }
  // Lm = beta .* strict(G)
  #pragma unroll
  for (int r = 0; r < 4; ++r) {
    int t = w * 16 + quad * 4 + r;
    float bv = bet[t];
    #pragma unroll
    for (int f = 0; f < 4; ++f) {
      int tp = f * 16 + lane15;
      Lm[t][tp] = (t > tp) ? bv * g[f][r] : 0.f;
    }
  }
  // stage WT[d][t] (transpose of whc)
  {
    int d0 = (tid & 7) * 8;
    #pragma unroll
    for (int it = 0; it < 2; ++it) {
      int t = it * 32 + (tid >> 3);
      uint4 pk = *(const uint4*)&whc[(long)t * HDIM + d0];
      const ushort* pu = (const ushort*)&pk;
      #pragma unroll
      for (int i = 0; i < 8; ++i) WT[(d0 + i) * LS + t] = pu[i];
    }
  }
  __syncthreads();

  // forward substitution: (I+Lm) Tbeta = diag(beta); wave w rows [16w,16w+16), lane = column
  {
    float cur[16];
    #pragma unroll
    for (int i = 0; i < 16; ++i) cur[i] = (w * 16 + i == l) ? bet[l] : 0.f;
    for (int sb = 0; sb < 4; ++sb) {
      if (w == sb) {
        float xloc[16];
        #pragma unroll
        for (int i = 0; i < 16; ++i) {
          float bv = cur[i];
          #pragma unroll
          for (int j2 = 0; j2 < 16; ++j2)
            if (j2 < i) bv -= Lm[sb * 16 + i][sb * 16 + j2] * xloc[j2];
          xloc[i] = bv;
          Vf[sb * 16 + i][l] = bv;
        }
      }
      __syncthreads();
      if (w > sb) {
        float xp[16];
        #pragma unroll
        for (int t = 0; t < 16; ++t) xp[t] = Vf[sb * 16 + t][l];
        #pragma unroll
        for (int i = 0; i < 16; ++i) {
          float s2 = cur[i];
          #pragma unroll
          for (int t = 0; t < 16; ++t) s2 -= Lm[w * 16 + i][sb * 16 + t] * xp[t];
          cur[i] = s2;
        }
      }
    }
  }
  // write TB bf16 + stage Tb LDS
  {
    int t = tid >> 2, off = (tid & 3) * 16;
    ushort tmp[16];
    #pragma unroll
    for (int i = 0; i < 16; ++i) { tmp[i] = f2b(Vf[t][off + i]); Tb[t * LS + off + i] = tmp[i]; }
    *(uint4*)&TBh[t * 64 + off] = *(const uint4*)&tmp[0];
    *(uint4*)&TBh[t * 64 + off + 8] = *(const uint4*)&tmp[8];
  }
  __syncthreads();
  // Yb[t][d] = sum_t' Tb[t][t'] * wh[t'][d] : A=Tb LDS, B=WT LDS
  f32x4 y[4] = {};
  #pragma unroll
  for (int s = 0; s < 2; ++s) {
    bf16x8 af = *(const bf16x8*)&Tb[(w * 16 + lane15) * LS + s * 32 + quad * 8];
    #pragma unroll
    for (int f = 0; f < 4; ++f) {
      bf16x8 bf = *(const bf16x8*)&WT[(f * 16 + lane15) * LS + s * 32 + quad * 8];
      y[f] = MFMA16(af, bf, y[f]);
    }
  }
  #pragma unroll
  for (int f = 0; f < 4; ++f)
    #pragma unroll
    for (int r = 0; r < 4; ++r)
      YBh[(long)(w * 16 + quad * 4 + r) * 64 + f * 16 + lane15] = f2b(y[f][r]);
}

// ---------------- solveB: per (col slab j, head h): chunk recurrence, writes X + PZ levels ----------------
__global__ __launch_bounds__(256) void solveB_kernel(
    const ushort* __restrict__ whb, const ushort* __restrict__ kb,
    const ushort* __restrict__ TB, const ushort* __restrict__ YB,
    ushort* __restrict__ Xb, ushort* __restrict__ PZ)
{
  int js = blockIdx.x, h = blockIdx.y;
  int j0 = js * 64;
  const ushort* wh_h = whb + (long)h * TTD * HDIM;
  const ushort* k_h = kb + (long)(h >> 1) * 64;
  ushort* X_h = Xb + (long)h * TTD * TTD;
  ushort* PZ_h = PZ + (long)h * 15 * TTD * HDIM;

  __shared__ ushort WT[64 * LS];  // wh^T chunk [d][t]
  __shared__ ushort XM[64 * LS];  // Mt then Xl [j][t]
  __shared__ ushort nS[64 * LS];  // -S [j][d]

  int tid = threadIdx.x, w = tid >> 6, l = tid & 63;
  int quad = l >> 4, lane15 = l & 15;
  f32x4 Sacc[4] = {}, Wacc[4] = {};

  for (int c = js; c < 16; ++c) {
    const ushort* whc = wh_h + (long)c * 64 * HDIM;
    __syncthreads();  // B0: protect WT/XM rewrite; nS writes visible
    // stage WT[d][t]
    {
      int d0 = (tid & 7) * 8;
      #pragma unroll
      for (int it = 0; it < 2; ++it) {
        int t = it * 32 + (tid >> 3);
        uint4 pk = *(const uint4*)&whc[(long)t * HDIM + d0];
        const ushort* pu = (const ushort*)&pk;
        #pragma unroll
        for (int i = 0; i < 8; ++i) WT[(d0 + i) * LS + t] = pu[i];
      }
    }
    f32x4 xacc[4] = {};
    if (c == js) {
      // M = wh.K^T (rows t, cols j), strict mask, stage Mt[j][t]
      f32x4 m[4] = {};
      #pragma unroll
      for (int s = 0; s < 2; ++s) {
        bf16x8 af = *(const bf16x8*)&whc[(long)(w * 16 + lane15) * HDIM + s * 32 + quad * 8];
        #pragma unroll
        for (int f = 0; f < 4; ++f) {
          bf16x8 bk = *(const bf16x8*)&k_h[(long)(j0 + f * 16 + lane15) * DDM + s * 32 + quad * 8];
          m[f] = MFMA16(af, bk, m[f]);
        }
      }
      #pragma unroll
      for (int f = 0; f < 4; ++f)
        #pragma unroll
        for (int r = 0; r < 4; ++r) {
          int t = w * 16 + quad * 4 + r, j = f * 16 + lane15;
          XM[j * LS + t] = (t > j) ? f2b(m[f][r]) : (ushort)0;
        }
      __syncthreads();  // B1: Mt visible
      // X = TB @ Mt
      const ushort* TBh = TB + ((long)h * 16 + c) * 4096;
      #pragma unroll
      for (int s = 0; s < 2; ++s) {
        bf16x8 af = *(const bf16x8*)&TBh[(long)(w * 16 + lane15) * 64 + s * 32 + quad * 8];
        #pragma unroll
        for (int f = 0; f < 4; ++f) {
          bf16x8 bf = *(const bf16x8*)&XM[(f * 16 + lane15) * LS + s * 32 + quad * 8];
          xacc[f] = MFMA16(af, bf, xacc[f]);
        }
      }
      __syncthreads();  // B1b: Mt reads done before Xl overwrite
    } else {
      // X = Yb.(K^T - S): B1 = K global, B2 = nS LDS
      const ushort* YBh = YB + ((long)h * 16 + c) * 4096;
      #pragma unroll
      for (int s = 0; s < 2; ++s) {
        bf16x8 af = *(const bf16x8*)&YBh[(long)(w * 16 + lane15) * 64 + s * 32 + quad * 8];
        #pragma unroll
        for (int f = 0; f < 4; ++f) {
          bf16x8 bk = *(const bf16x8*)&k_h[(long)(j0 + f * 16 + lane15) * DDM + s * 32 + quad * 8];
          xacc[f] = MFMA16(af, bk, xacc[f]);
          bf16x8 bs = *(const bf16x8*)&nS[(f * 16 + lane15) * LS + s * 32 + quad * 8];
          xacc[f] = MFMA16(af, bs, xacc[f]);
        }
      }
    }
    // stage Xl[j][t]
    #pragma unroll
    for (int f = 0; f < 4; ++f)
      #pragma unroll
      for (int r = 0; r < 4; ++r)
        XM[(f * 16 + lane15) * LS + w * 16 + quad * 4 + r] = f2b(xacc[f][r]);
    __syncthreads();  // B2: Xl + WT visible
    // global X write (coalesced)
    {
      int j = tid >> 2, seg = (tid & 3) * 16;
      uint2 a0 = *(const uint2*)&XM[j * LS + seg];
      uint2 a1 = *(const uint2*)&XM[j * LS + seg + 4];
      uint2 a2 = *(const uint2*)&XM[j * LS + seg + 8];
      uint2 a3 = *(const uint2*)&XM[j * LS + seg + 12];
      uint4 s0 = {a0.x, a0.y, a1.x, a1.y};
      uint4 s1 = {a2.x, a2.y, a3.x, a3.y};
      *(uint4*)&X_h[(long)(j0 + j) * TTD + c * 64 + seg] = s0;
      *(uint4*)&X_h[(long)(j0 + j) * TTD + c * 64 + seg + 8] = s1;
    }
    if (c < 15) {
      // S[d][j] += WT @ Xl ; W[j][d] += Xl @ WT
      #pragma unroll
      for (int s = 0; s < 2; ++s) {
        bf16x8 aw = *(const bf16x8*)&WT[(w * 16 + lane15) * LS + s * 32 + quad * 8];
        bf16x8 ax = *(const bf16x8*)&XM[(w * 16 + lane15) * LS + s * 32 + quad * 8];
        #pragma unroll
        for (int f = 0; f < 4; ++f) {
          bf16x8 bx = *(const bf16x8*)&XM[(f * 16 + lane15) * LS + s * 32 + quad * 8];
          Sacc[f] = MFMA16(aw, bx, Sacc[f]);
          bf16x8 bw2 = *(const bf16x8*)&WT[(f * 16 + lane15) * LS + s * 32 + quad * 8];
          Wacc[f] = MFMA16(ax, bw2, Wacc[f]);
        }
      }
      // PZ level c (negated prefix for i0 = c+1)
      ushort* pz = PZ_h + (long)c * TTD * HDIM;
      #pragma unroll
      for (int f = 0; f < 4; ++f)
        #pragma unroll
        for (int r = 0; r < 4; ++r)
          pz[(long)(j0 + w * 16 + quad * 4 + r) * 64 + f * 16 + lane15] = f2b(-Wacc[f][r]);
      // refresh nS[j][d] = -S
      #pragma unroll
      for (int f = 0; f < 4; ++f)
        #pragma unroll
        for (int r = 0; r < 4; ++r)
          nS[(f * 16 + lane15) * LS + w * 16 + quad * 4 + r] = f2b(-Sacc[f][r]);
    }
  }
}

// ---------------- flash: fused qk - q.PZ - qwD.X^T -> online softmax -> PV ----------------
__global__ __launch_bounds__(256) void flash_kernel(
    const ushort* __restrict__ qb, const ushort* __restrict__ kbuf,
    const ushort* __restrict__ whb, const ushort* __restrict__ Xb,
    const ushort* __restrict__ PZ, const ushort* __restrict__ vTb,
    ushort* __restrict__ oall)
{
  int p = blockIdx.x, h = blockIdx.y;
  const ushort* q_h = qb + (long)(h >> 1) * 64;
  const ushort* k_h = kbuf + (long)(h >> 1) * 64;
  const ushort* wh_h = whb + (long)h * TTD * HDIM;
  const ushort* X_h = Xb + (long)h * TTD * TTD;
  const ushort* PZ_h = PZ + (long)h * 15 * TTD * HDIM;
  const ushort* v_h = vTb + (long)(h >> 1) * 64 * TTD;

  __shared__ ushort QWD[64 * LS];
  __shared__ ushort PT[64 * LS];

  int tid = threadIdx.x, w = tid >> 6, l = tid & 63;
  int quad = l >> 4, lane15 = l & 15;

  for (int half = 0; half < 2; ++half) {
    int ri = half ? (15 - p) : p;
    int r0 = ri * 64;
    __syncthreads();  // LDS reuse across halves
    // hoist q A-frags for this row tile
    bf16x8 aq[2];
    #pragma unroll
    for (int s = 0; s < 2; ++s)
      aq[s] = *(const bf16x8*)&q_h[(long)(r0 + w * 16 + lane15) * DDM + s * 32 + quad * 8];
    // qwD = -incl(q.wh^T) staged [i][t]
    {
      f32x4 t4[4] = {};
      #pragma unroll
      for (int s = 0; s < 2; ++s)
        #pragma unroll
        for (int f = 0; f < 4; ++f) {
          bf16x8 bf = *(const bf16x8*)&wh_h[(long)(r0 + f * 16 + lane15) * HDIM + s * 32 + quad * 8];
          t4[f] = MFMA16(aq[s], bf, t4[f]);
        }
      #pragma unroll
      for (int f = 0; f < 4; ++f)
        #pragma unroll
        for (int r = 0; r < 4; ++r) {
          int i = w * 16 + quad * 4 + r, t = f * 16 + lane15;
          QWD[i * LS + t] = (i >= t) ? f2b(-t4[f][r]) : (ushort)0;
        }
    }
    __syncthreads();

    f32x4 O[4] = {};
    float m[4], lsum[4];
    #pragma unroll
    for (int r = 0; r < 4; ++r) { m[r] = -1e30f; lsum[r] = 0.f; }

    for (int jb = 0; jb <= ri; ++jb) {
      int c0 = jb * 64;
      f32x4 acc[4] = {};
      // qk
      #pragma unroll
      for (int s = 0; s < 2; ++s)
        #pragma unroll
        for (int f = 0; f < 4; ++f) {
          bf16x8 bk = *(const bf16x8*)&k_h[(long)(c0 + f * 16 + lane15) * DDM + s * 32 + quad * 8];
          acc[f] = MFMA16(aq[s], bk, acc[f]);
        }
      // - q.PZ  (PZ stored negated)
      if (jb < ri) {
        const ushort* pz = PZ_h + (long)(ri - 1) * TTD * HDIM;
        #pragma unroll
        for (int s = 0; s < 2; ++s)
          #pragma unroll
          for (int f = 0; f < 4; ++f) {
            bf16x8 bz = *(const bf16x8*)&pz[(long)(c0 + f * 16 + lane15) * HDIM + s * 32 + quad * 8];
            acc[f] = MFMA16(aq[s], bz, acc[f]);
          }
      }
      // - qwD.X^T (qwD negated)
      #pragma unroll
      for (int s = 0; s < 2; ++s) {
        bf16x8 aw = *(const bf16x8*)&QWD[(w * 16 + lane15) * LS + s * 32 + quad * 8];
        #pragma unroll
        for (int f = 0; f < 4; ++f) {
          bf16x8 bx = *(const bf16x8*)&X_h[(long)(c0 + f * 16 + lane15) * TTD + r0 + s * 32 + quad * 8];
          acc[f] = MFMA16(aw, bx, acc[f]);
        }
      }
      // online softmax
      float rmax[4] = {-3e38f, -3e38f, -3e38f, -3e38f};
      #pragma unroll
      for (int f = 0; f < 4; ++f)
        #pragma unroll
        for (int r = 0; r < 4; ++r) {
          float lv = acc[f][r] * PSCALE;
          if (jb == ri && (f * 16 + lane15) > (w * 16 + quad * 4 + r)) lv = -3e38f;
          acc[f][r] = lv;
          rmax[r] = fmaxf(rmax[r], lv);
        }
      #pragma unroll
      for (int r = 0; r < 4; ++r) {
        rmax[r] = fmaxf(rmax[r], __shfl_xor(rmax[r], 1, 64));
        rmax[r] = fmaxf(rmax[r], __shfl_xor(rmax[r], 2, 64));
        rmax[r] = fmaxf(rmax[r], __shfl_xor(rmax[r], 4, 64));
        rmax[r] = fmaxf(rmax[r], __shfl_xor(rmax[r], 8, 64));
      }
      float alpha[4], rs[4] = {0.f, 0.f, 0.f, 0.f};
      #pragma unroll
      for (int r = 0; r < 4; ++r) {
        float nm = fmaxf(m[r], rmax[r]);
        alpha[r] = __expf(m[r] - nm);
        m[r] = nm;
      }
      #pragma unroll
      for (int f = 0; f < 4; ++f)
        #pragma unroll
        for (int r = 0; r < 4; ++r) {
          float e = __expf(acc[f][r] - m[r]);
          acc[f][r] = e;
          rs[r] += e;
        }
      #pragma unroll
      for (int r = 0; r < 4; ++r) {
        rs[r] += __shfl_xor(rs[r], 1, 64);
        rs[r] += __shfl_xor(rs[r], 2, 64);
        rs[r] += __shfl_xor(rs[r], 4, 64);
        rs[r] += __shfl_xor(rs[r], 8, 64);
        lsum[r] = lsum[r] * alpha[r] + rs[r];
      }
      #pragma unroll
      for (int f = 0; f < 4; ++f)
        #pragma unroll
        for (int r = 0; r < 4; ++r) O[f][r] *= alpha[r];
      // stage P [i][j]
      #pragma unroll
      for (int f = 0; f < 4; ++f)
        #pragma unroll
        for (int r = 0; r < 4; ++r)
          PT[(w * 16 + quad * 4 + r) * LS + f * 16 + lane15] = f2b(acc[f][r]);
      __syncthreads();
      // PV
      #pragma unroll
      for (int s = 0; s < 2; ++s) {
        bf16x8 ap = *(const bf16x8*)&PT[(w * 16 + lane15) * LS + s * 32 + quad * 8];
        #pragma unroll
        for (int f = 0; f < 4; ++f) {
          bf16x8 bv = *(const bf16x8*)&v_h[(long)(f * 16 + lane15) * TTD + c0 + s * 32 + quad * 8];
          O[f] = MFMA16(ap, bv, O[f]);
        }
      }
      __syncthreads();
    }
    // epilogue
    #pragma unroll
    for (int r = 0; r < 4; ++r) lsum[r] = 1.f / lsum[r];
    #pragma unroll
    for (int f = 0; f < 4; ++f)
      #pragma unroll
      for (int r = 0; r < 4; ++r)
        oall[(long)(r0 + w * 16 + quad * 4 + r) * 2048 + h * 64 + f * 16 + lane15] =
            f2b(O[f][r] * lsum[r]);
  }
}

// ---------------- conv(K=3)+SiLU+rotate+normalize -> wh bf16 ----------------
__global__ __launch_bounds__(256) void convdir_kernel(
    const float* __restrict__ w_raw, const float* __restrict__ conv_w,
    const float* __restrict__ omega, const float* __restrict__ phi,
    ushort* __restrict__ whb)
{
  int gid = blockIdx.x * 256 + threadIdx.x;
  int lane = gid & 63;
  int w = gid >> 6;
  int hr = w & 31, t = w >> 5;
  int hkv = hr >> 1, r = hr & 1;
  int cA = hkv * 256 + r * 128 + lane;
  int cB = cA + 64;
  float a = 0.f, b = 0.f;
  #pragma unroll
  for (int i = 0; i < 3; ++i) {
    int tp = t - 2 + i;
    if (tp >= 0) {
      a += w_raw[(long)tp * NOUTW + cA] * conv_w[cA * 3 + i];
      b += w_raw[(long)tp * NOUTW + cB] * conv_w[cB * 3 + i];
    }
  }
  a = a / (1.f + expf(-a));
  b = b / (1.f + expf(-b));
  float th = omega[r] * (float)t + phi[r];
  float wd = a * cosf(th) + b * sinf(th);
  float ss = wd * wd;
  #pragma unroll
  for (int o = 32; o > 0; o >>= 1) ss += __shfl_xor(ss, o, 64);
  float inv = 1.f / sqrtf(ss + 1e-6f);
  whb[((long)hr * TTD + t) * HDIM + lane] = f2b(wd * inv);
}

__global__ __launch_bounds__(256) void beta_kernel(
    const float* __restrict__ bt_lin, const float* __restrict__ bt_b,
    float* __restrict__ beta)
{
  int idx = blockIdx.x * 256 + threadIdx.x;
  int t = idx >> 5, hr = idx & 31;
  float x = bt_lin[t * 32 + hr] + bt_b[hr];
  beta[(long)hr * TTD + t] = 2.f / (1.f + expf(-x));
}

// ---------------- host ----------------
extern "C" void kernel_launch(void* const* d_in, const int* in_sizes, int n_in,
                              void* d_out, int out_size, void* d_ws, size_t ws_size,
                              hipStream_t stream) {
  const float* hs     = (const float*)d_in[0];
  const float* q_w    = (const float*)d_in[1];
  const float* k_w    = (const float*)d_in[2];
  const float* v_w    = (const float*)d_in[3];
  const float* w1     = (const float*)d_in[4];
  const float* w2     = (const float*)d_in[5];
  const float* conv_w = (const float*)d_in[6];
  const float* bt_w   = (const float*)d_in[7];
  const float* bt_b   = (const float*)d_in[8];
  const float* o_w    = (const float*)d_in[9];
  const float* omega  = (const float*)d_in[10];
  const float* phi    = (const float*)d_in[11];
  float* out = (float*)d_out;
  char* ws = (char*)d_ws;

  ushort* Xb     = (ushort*)(ws + OFF_X);
  ushort* PZ     = (ushort*)(ws + OFF_PZ);
  ushort* hs_b   = (ushort*)(ws + OFF_HSB);
  ushort* qw_wb  = (ushort*)(ws + OFF_QWW);
  ushort* kw_wb  = (ushort*)(ws + OFF_KWW);
  ushort* vw_wb  = (ushort*)(ws + OFF_VWW);
  ushort* w2_b   = (ushort*)(ws + OFF_W2B);
  ushort* wlow_b = (ushort*)(ws + OFF_WLOWB);
  float*  w_raw  = (float*)(ws + OFF_WRAW);
  ushort* ow_b   = (ushort*)(ws + OFF_OWB);
  ushort* TB     = (ushort*)(ws + OFF_TB);
  ushort* o_all  = (ushort*)(ws + OFF_OALL);
  ushort* YB     = (ushort*)(ws + OFF_YB);
  ushort* wh_b   = (ushort*)(ws + OFF_WHB);
  ushort* q_b    = (ushort*)(ws + OFF_QB);
  ushort* k_b    = (ushort*)(ws + OFF_KB);
  ushort* vT_b   = (ushort*)(ws + OFF_VTB);
  float*  beta   = (float*)(ws + OFF_BETA);
  float*  bt_lin = (float*)(ws + OFF_BTL);
  ushort* bw_b   = (ushort*)(ws + OFF_BW64);

  // converts (o_w converted later, after flash frees the PZ region)
  cvt_kernel<<<dim3(1024), 256, 0, stream>>>(hs,  hs_b,  (long)TTD * DDM);
  cvt_kernel<<<dim3(1024), 256, 0, stream>>>(q_w, qw_wb, (long)DDM * DDM);
  cvt_kernel<<<dim3(1024), 256, 0, stream>>>(k_w, kw_wb, (long)DDM * DDM);
  cvt_kernel<<<dim3(1024), 256, 0, stream>>>(v_w, vw_wb, (long)DDM * DDM);
  cvt_kernel<<<dim3(128),  256, 0, stream>>>(w2,  w2_b,  (long)NOUTW * 32);
  cvt_kernel<<<dim3(32),   256, 0, stream>>>(bt_w, bw_b,            (long)32 * DDM);
  cvt_kernel<<<dim3(32),   256, 0, stream>>>(w1,   bw_b + 32 * DDM, (long)32 * DDM);

  smallproj_kernel<<<dim3(16), 256, 0, stream>>>(hs_b, bw_b, bt_lin, wlow_b);
  beta_kernel<<<dim3(128), 256, 0, stream>>>(bt_lin, bt_b, beta);

  mfma_nt_kernel<<<dim3(16, 16), 256, 0, stream>>>(hs_b, DDM, qw_wb, DDM, q_b,  DDM, DDM, ONT_B16);
  mfma_nt_kernel<<<dim3(16, 16), 256, 0, stream>>>(hs_b, DDM, kw_wb, DDM, k_b,  DDM, DDM, ONT_B16);
  mfma_nt_kernel<<<dim3(16, 16), 256, 0, stream>>>(hs_b, DDM, vw_wb, DDM, vT_b, DDM, DDM, ONT_B16T);
  mfma_nt_kernel<<<dim3(64, 16), 256, 0, stream>>>(wlow_b, 32, w2_b, 32, w_raw, NOUTW, 32, ONT_F32);

  convdir_kernel<<<dim3(8192), 256, 0, stream>>>(w_raw, conv_w, omega, phi, wh_b);

  solveA_kernel<<<dim3(16, 32), 256, 0, stream>>>(wh_b, beta, TB, YB);
  solveB_kernel<<<dim3(16, 32), 256, 0, stream>>>(wh_b, k_b, TB, YB, Xb, PZ);

  // flash writes o_all over the (now dead) TB region
  flash_kernel<<<dim3(8, 32), 256, 0, stream>>>(q_b, k_b, wh_b, Xb, PZ, vT_b, o_all);

  // o_w convert into (now dead) PZ region, then final GEMM
  cvt_kernel<<<dim3(2048), 256, 0, stream>>>(o_w, ow_b, (long)DDM * 2048);
  mfma_nt_kernel<<<dim3(16, 16), 256, 0, stream>>>(o_all, 2048, ow_b, 2048, out, DDM, 2048, ONT_F32);

  (void)in_sizes; (void)n_in; (void)out_size; (void)ws_size;
}

// Round 5
// 318.516 us; speedup vs baseline: 23.5919x; 1.1958x over previous
//
#include <hip/hip_runtime.h>
#include <math.h>

// ---------------- problem constants ----------------
#define TTD 1024
#define DDM 1024
#define HDIM 64
#define NOUTW 4096
#define PSCALE 0.125f
#define LS 72   // LDS leading stride in bf16 elems

typedef __attribute__((ext_vector_type(8))) __bf16 bf16x8;
typedef __attribute__((ext_vector_type(4))) float f32x4;
#define MFMA16(a,b,c) __builtin_amdgcn_mfma_f32_16x16x32_bf16(a,b,c,0,0,0)

__device__ __forceinline__ ushort f2b(float f) {
  unsigned u = __builtin_bit_cast(unsigned, f);
  return (ushort)((u + 0x7fffu + ((u >> 16) & 1u)) >> 16);
}

__device__ __forceinline__ void gload_lds16(const ushort* g, ushort* l) {
  __builtin_amdgcn_global_load_lds(
      (const __attribute__((address_space(1))) unsigned*)g,
      (__attribute__((address_space(3))) unsigned*)l, 16, 0, 0);
}

// ---------------- workspace layout (bytes); total = 149,291,008 (proven) ----------------
#define OFF_X     0L            // X bf16 [32][1024 j][1024 t] : 64 MiB
#define OFF_PZ    67108864L     // PZ bf16 [32][15][1024 j][64 d] : 60 MiB (negated prefix)
// aliases inside PZ (all dead before solveB writes PZ):
#define OFF_HSB   67108864L
#define OFF_QWW   69206016L
#define OFF_KWW   71303168L
#define OFF_VWW   73400320L
#define OFF_W2B   75497472L
#define OFF_WLOWB 75759616L
#define OFF_WRAW  83886080L     // fp32 1024x4096, dead after convdir
#define OFF_TB    130023424L    // Tbeta bf16 ; o_all aliases after solveB consumes it
#define OFF_OALL  130023424L
#define OFF_YB    134217728L
#define OFF_WHB   138412032L
#define OFF_QB    142606336L
#define OFF_KB    144703488L
#define OFF_VTB   146800640L
#define OFF_BETA  148897792L
#define OFF_BW64  149159936L    // 64x1024 bf16 [bt_w ; w1]

// ---------------- merged fp32 -> bf16 convert (7 segments, one launch) ----------------
struct CvtSegs {
  const float* src[7];
  ushort* dst[7];
  long cnt[7];
};
__global__ __launch_bounds__(256) void cvt_all_kernel(CvtSegs sg) {
  long e = ((long)blockIdx.x * 256 + threadIdx.x) * 4;
  #pragma unroll
  for (int s = 0; s < 7; ++s) {
    if (e < sg.cnt[s]) {
      float4 f = *(const float4*)(sg.src[s] + e);
      ushort4 o;
      o.x = f2b(f.x); o.y = f2b(f.y); o.z = f2b(f.z); o.w = f2b(f.w);
      *(ushort4*)(sg.dst[s] + e) = o;
      return;
    }
    e -= sg.cnt[s];
  }
}

// ---------------- fused QKV projections: z selects weight/output ----------------
__global__ __launch_bounds__(256) void qkv_kernel(
    const ushort* __restrict__ hsb,
    const ushort* __restrict__ wq, const ushort* __restrict__ wk, const ushort* __restrict__ wv,
    ushort* __restrict__ cq, ushort* __restrict__ ck, ushort* __restrict__ cv)
{
  int z = blockIdx.z;
  const ushort* B = (z == 0) ? wq : (z == 1) ? wk : wv;
  __shared__ ushort As[64 * 32];
  __shared__ ushort Bs[64 * 32];
  int tid = threadIdx.x, w = tid >> 6, l = tid & 63;
  int quad = l >> 4, lane15 = l & 15;
  int rm = blockIdx.y * 64, cn = blockIdx.x * 64;
  int row = tid >> 2, ch = (tid & 3) * 8;
  f32x4 acc[4] = {};
  for (int k0 = 0; k0 < 1024; k0 += 32) {
    gload_lds16(hsb + (long)(rm + row) * DDM + k0 + ch, &As[tid * 8]);
    gload_lds16(B + (long)(cn + row) * DDM + k0 + ch, &Bs[tid * 8]);
    __syncthreads();
    bf16x8 af = *(const bf16x8*)&As[(w * 16 + lane15) * 32 + quad * 8];
    #pragma unroll
    for (int f = 0; f < 4; ++f) {
      bf16x8 bf = *(const bf16x8*)&Bs[(f * 16 + lane15) * 32 + quad * 8];
      acc[f] = MFMA16(af, bf, acc[f]);
    }
    __syncthreads();
  }
  int orow = rm + w * 16 + quad * 4;
  if (z < 2) {
    ushort* Cb = (z == 0) ? cq : ck;
    #pragma unroll
    for (int f = 0; f < 4; ++f)
      #pragma unroll
      for (int r = 0; r < 4; ++r)
        Cb[(long)(orow + r) * DDM + cn + f * 16 + lane15] = f2b(acc[f][r]);
  } else {
    #pragma unroll
    for (int f = 0; f < 4; ++f) {
      ushort4 o;
      o.x = f2b(acc[f][0]); o.y = f2b(acc[f][1]);
      o.z = f2b(acc[f][2]); o.w = f2b(acc[f][3]);
      *(ushort4*)&cv[(long)(cn + f * 16 + lane15) * TTD + orow] = o;
    }
  }
}

// ---------------- w_raw GEMM (K=32): w_raw = w_low @ w2^T, fp32 out ----------------
__global__ __launch_bounds__(256) void wraw_kernel(
    const ushort* __restrict__ A, const ushort* __restrict__ B, float* __restrict__ C)
{
  __shared__ ushort As[64 * 32];
  __shared__ ushort Bs[64 * 32];
  int tid = threadIdx.x, w = tid >> 6, l = tid & 63;
  int quad = l >> 4, lane15 = l & 15;
  int rm = blockIdx.y * 64, cn = blockIdx.x * 64;
  int row = tid >> 2, ch = (tid & 3) * 8;
  f32x4 acc[4] = {};
  gload_lds16(A + (long)(rm + row) * 32 + ch, &As[tid * 8]);
  gload_lds16(B + (long)(cn + row) * 32 + ch, &Bs[tid * 8]);
  __syncthreads();
  bf16x8 af = *(const bf16x8*)&As[(w * 16 + lane15) * 32 + quad * 8];
  #pragma unroll
  for (int f = 0; f < 4; ++f) {
    bf16x8 bf = *(const bf16x8*)&Bs[(f * 16 + lane15) * 32 + quad * 8];
    acc[f] = MFMA16(af, bf, acc[f]);
  }
  int orow = rm + w * 16 + quad * 4;
  #pragma unroll
  for (int f = 0; f < 4; ++f)
    #pragma unroll
    for (int r = 0; r < 4; ++r)
      C[(long)(orow + r) * NOUTW + cn + f * 16 + lane15] = acc[f][r];
}

// ---------------- small projections + fused beta: bt/w1 stacked weights ----------------
__global__ __launch_bounds__(256) void smallproj_kernel(
    const ushort* __restrict__ hsb, const ushort* __restrict__ bw,
    const float* __restrict__ bt_b, float* __restrict__ beta,
    ushort* __restrict__ wlowb)
{
  int rm = blockIdx.x * 64;
  int tid = threadIdx.x, w = tid >> 6, l = tid & 63;
  int quad = l >> 4, lane15 = l & 15;
  f32x4 acc[4] = {};
  for (int k0 = 0; k0 < 1024; k0 += 32) {
    bf16x8 af = *(const bf16x8*)&hsb[(long)(rm + w * 16 + lane15) * 1024 + k0 + quad * 8];
    #pragma unroll
    for (int f = 0; f < 4; ++f) {
      bf16x8 bf = *(const bf16x8*)&bw[(long)(f * 16 + lane15) * 1024 + k0 + quad * 8];
      acc[f] = MFMA16(af, bf, acc[f]);
    }
  }
  int orow = rm + w * 16 + quad * 4;
  #pragma unroll
  for (int f = 0; f < 2; ++f) {
    int hr = f * 16 + lane15;
    float bb = bt_b[hr];
    #pragma unroll
    for (int r = 0; r < 4; ++r)
      beta[(long)hr * TTD + orow + r] = 2.f / (1.f + expf(-(acc[f][r] + bb)));
  }
  #pragma unroll
  for (int f = 2; f < 4; ++f)
    #pragma unroll
    for (int r = 0; r < 4; ++r)
      wlowb[(long)(orow + r) * 32 + (f - 2) * 16 + lane15] = f2b(acc[f][r]);
}

// ---------------- solveA: Tbeta = (I+Lm)^-1 diag(beta), Yb = Tbeta.wh ----------------
__global__ __launch_bounds__(256) void solveA_kernel(
    const ushort* __restrict__ whb, const float* __restrict__ beta,
    ushort* __restrict__ TB, ushort* __restrict__ YB)
{
  int c = blockIdx.x, h = blockIdx.y;
  const ushort* whc = whb + ((long)h * TTD + c * 64) * HDIM;
  const float* bet = beta + (long)h * TTD + c * 64;
  ushort* TBh = TB + ((long)h * 16 + c) * 4096;
  ushort* YBh = YB + ((long)h * 16 + c) * 4096;

  __shared__ float Lm[64][65];
  __shared__ float Vf[64][65];
  __shared__ ushort WT[64 * LS];
  __shared__ ushort Tb[64 * LS];

  int tid = threadIdx.x, w = tid >> 6, l = tid & 63;
  int quad = l >> 4, lane15 = l & 15;

  f32x4 g[4] = {};
  #pragma unroll
  for (int s = 0; s < 2; ++s) {
    bf16x8 af = *(const bf16x8*)&whc[(long)(w * 16 + lane15) * HDIM + s * 32 + quad * 8];
    #pragma unroll
    for (int f = 0; f < 4; ++f) {
      bf16x8 bf = *(const bf16x8*)&whc[(long)(f * 16 + lane15) * HDIM + s * 32 + quad * 8];
      g[f] = MFMA16(af, bf, g[f]);
    }
  }
  #pragma unroll
  for (int r = 0; r < 4; ++r) {
    int t = w * 16 + quad * 4 + r;
    float bv = bet[t];
    #pragma unroll
    for (int f = 0; f < 4; ++f) {
      int tp = f * 16 + lane15;
      Lm[t][tp] = (t > tp) ? bv * g[f][r] : 0.f;
    }
  }
  {
    int d0 = (tid & 7) * 8;
    #pragma unroll
    for (int it = 0; it < 2; ++it) {
      int t = it * 32 + (tid >> 3);
      uint4 pk = *(const uint4*)&whc[(long)t * HDIM + d0];
      const ushort* pu = (const ushort*)&pk;
      #pragma unroll
      for (int i = 0; i < 8; ++i) WT[(d0 + i) * LS + t] = pu[i];
    }
  }
  __syncthreads();

  {
    float cur[16];
    #pragma unroll
    for (int i = 0; i < 16; ++i) cur[i] = (w * 16 + i == l) ? bet[l] : 0.f;
    for (int sb = 0; sb < 4; ++sb) {
      if (w == sb) {
        float xloc[16];
        #pragma unroll
        for (int i = 0; i < 16; ++i) {
          float bv = cur[i];
          #pragma unroll
          for (int j2 = 0; j2 < 16; ++j2)
            if (j2 < i) bv -= Lm[sb * 16 + i][sb * 16 + j2] * xloc[j2];
          xloc[i] = bv;
          Vf[sb * 16 + i][l] = bv;
        }
      }
      __syncthreads();
      if (w > sb) {
        float xp[16];
        #pragma unroll
        for (int t = 0; t < 16; ++t) xp[t] = Vf[sb * 16 + t][l];
        #pragma unroll
        for (int i = 0; i < 16; ++i) {
          float s2 = cur[i];
          #pragma unroll
          for (int t = 0; t < 16; ++t) s2 -= Lm[w * 16 + i][sb * 16 + t] * xp[t];
          cur[i] = s2;
        }
      }
    }
  }
  {
    int t = tid >> 2, off = (tid & 3) * 16;
    ushort tmp[16];
    #pragma unroll
    for (int i = 0; i < 16; ++i) { tmp[i] = f2b(Vf[t][off + i]); Tb[t * LS + off + i] = tmp[i]; }
    *(uint4*)&TBh[t * 64 + off] = *(const uint4*)&tmp[0];
    *(uint4*)&TBh[t * 64 + off + 8] = *(const uint4*)&tmp[8];
  }
  __syncthreads();
  f32x4 y[4] = {};
  #pragma unroll
  for (int s = 0; s < 2; ++s) {
    bf16x8 af = *(const bf16x8*)&Tb[(w * 16 + lane15) * LS + s * 32 + quad * 8];
    #pragma unroll
    for (int f = 0; f < 4; ++f) {
      bf16x8 bf = *(const bf16x8*)&WT[(f * 16 + lane15) * LS + s * 32 + quad * 8];
      y[f] = MFMA16(af, bf, y[f]);
    }
  }
  #pragma unroll
  for (int f = 0; f < 4; ++f)
    #pragma unroll
    for (int r = 0; r < 4; ++r)
      YBh[(long)(w * 16 + quad * 4 + r) * 64 + f * 16 + lane15] = f2b(y[f][r]);
}

// ---------------- solveB: chunk recurrence per (head, col slab), balanced swizzle ----------------
__global__ __launch_bounds__(256) void solveB_kernel(
    const ushort* __restrict__ whb, const ushort* __restrict__ kb,
    const ushort* __restrict__ TB, const ushort* __restrict__ YB,
    ushort* __restrict__ Xb, ushort* __restrict__ PZ)
{
  int h = blockIdx.x;
  int ty = blockIdx.y;
  int js = (ty < 8) ? ty : (23 - ty);   // blocks n,n+256 get js & 15-js: balanced
  int j0 = js * 64;
  const ushort* wh_h = whb + (long)h * TTD * HDIM;
  const ushort* k_h = kb + (long)(h >> 1) * 64;
  ushort* X_h = Xb + (long)h * TTD * TTD;
  ushort* PZ_h = PZ + (long)h * 15 * TTD * HDIM;

  __shared__ ushort WT[64 * LS];
  __shared__ ushort XM[64 * LS];
  __shared__ ushort nS[64 * LS];

  int tid = threadIdx.x, w = tid >> 6, l = tid & 63;
  int quad = l >> 4, lane15 = l & 15;
  f32x4 Sacc[4] = {}, Wacc[4] = {};

  for (int c = js; c < 16; ++c) {
    const ushort* whc = wh_h + (long)c * 64 * HDIM;
    __syncthreads();
    {
      int d0 = (tid & 7) * 8;
      #pragma unroll
      for (int it = 0; it < 2; ++it) {
        int t = it * 32 + (tid >> 3);
        uint4 pk = *(const uint4*)&whc[(long)t * HDIM + d0];
        const ushort* pu = (const ushort*)&pk;
        #pragma unroll
        for (int i = 0; i < 8; ++i) WT[(d0 + i) * LS + t] = pu[i];
      }
    }
    f32x4 xacc[4] = {};
    if (c == js) {
      f32x4 m[4] = {};
      #pragma unroll
      for (int s = 0; s < 2; ++s) {
        bf16x8 af = *(const bf16x8*)&whc[(long)(w * 16 + lane15) * HDIM + s * 32 + quad * 8];
        #pragma unroll
        for (int f = 0; f < 4; ++f) {
          bf16x8 bk = *(const bf16x8*)&k_h[(long)(j0 + f * 16 + lane15) * DDM + s * 32 + quad * 8];
          m[f] = MFMA16(af, bk, m[f]);
        }
      }
      #pragma unroll
      for (int f = 0; f < 4; ++f)
        #pragma unroll
        for (int r = 0; r < 4; ++r) {
          int t = w * 16 + quad * 4 + r, j = f * 16 + lane15;
          XM[j * LS + t] = (t > j) ? f2b(m[f][r]) : (ushort)0;
        }
      __syncthreads();
      const ushort* TBh = TB + ((long)h * 16 + c) * 4096;
      #pragma unroll
      for (int s = 0; s < 2; ++s) {
        bf16x8 af = *(const bf16x8*)&TBh[(long)(w * 16 + lane15) * 64 + s * 32 + quad * 8];
        #pragma unroll
        for (int f = 0; f < 4; ++f) {
          bf16x8 bf = *(const bf16x8*)&XM[(f * 16 + lane15) * LS + s * 32 + quad * 8];
          xacc[f] = MFMA16(af, bf, xacc[f]);
        }
      }
      __syncthreads();
    } else {
      const ushort* YBh = YB + ((long)h * 16 + c) * 4096;
      #pragma unroll
      for (int s = 0; s < 2; ++s) {
        bf16x8 af = *(const bf16x8*)&YBh[(long)(w * 16 + lane15) * 64 + s * 32 + quad * 8];
        #pragma unroll
        for (int f = 0; f < 4; ++f) {
          bf16x8 bk = *(const bf16x8*)&k_h[(long)(j0 + f * 16 + lane15) * DDM + s * 32 + quad * 8];
          xacc[f] = MFMA16(af, bk, xacc[f]);
          bf16x8 bs = *(const bf16x8*)&nS[(f * 16 + lane15) * LS + s * 32 + quad * 8];
          xacc[f] = MFMA16(af, bs, xacc[f]);
        }
      }
    }
    #pragma unroll
    for (int f = 0; f < 4; ++f)
      #pragma unroll
      for (int r = 0; r < 4; ++r)
        XM[(f * 16 + lane15) * LS + w * 16 + quad * 4 + r] = f2b(xacc[f][r]);
    __syncthreads();
    {
      int j = tid >> 2, seg = (tid & 3) * 16;
      uint2 a0 = *(const uint2*)&XM[j * LS + seg];
      uint2 a1 = *(const uint2*)&XM[j * LS + seg + 4];
      uint2 a2 = *(const uint2*)&XM[j * LS + seg + 8];
      uint2 a3 = *(const uint2*)&XM[j * LS + seg + 12];
      uint4 s0 = {a0.x, a0.y, a1.x, a1.y};
      uint4 s1 = {a2.x, a2.y, a3.x, a3.y};
      *(uint4*)&X_h[(long)(j0 + j) * TTD + c * 64 + seg] = s0;
      *(uint4*)&X_h[(long)(j0 + j) * TTD + c * 64 + seg + 8] = s1;
    }
    if (c < 15) {
      #pragma unroll
      for (int s = 0; s < 2; ++s) {
        bf16x8 aw = *(const bf16x8*)&WT[(w * 16 + lane15) * LS + s * 32 + quad * 8];
        bf16x8 ax = *(const bf16x8*)&XM[(w * 16 + lane15) * LS + s * 32 + quad * 8];
        #pragma unroll
        for (int f = 0; f < 4; ++f) {
          bf16x8 bx = *(const bf16x8*)&XM[(f * 16 + lane15) * LS + s * 32 + quad * 8];
          Sacc[f] = MFMA16(aw, bx, Sacc[f]);
          bf16x8 bw2 = *(const bf16x8*)&WT[(f * 16 + lane15) * LS + s * 32 + quad * 8];
          Wacc[f] = MFMA16(ax, bw2, Wacc[f]);
        }
      }
      ushort* pz = PZ_h + (long)c * TTD * HDIM;
      #pragma unroll
      for (int f = 0; f < 4; ++f)
        #pragma unroll
        for (int r = 0; r < 4; ++r)
          pz[(long)(j0 + w * 16 + quad * 4 + r) * 64 + f * 16 + lane15] = f2b(-Wacc[f][r]);
      #pragma unroll
      for (int f = 0; f < 4; ++f)
        #pragma unroll
        for (int r = 0; r < 4; ++r)
          nS[(f * 16 + lane15) * LS + w * 16 + quad * 4 + r] = f2b(-Sacc[f][r]);
    }
  }
}

// ---------------- flash: one row tile per block, register-prefetched streams ----------------
__global__ __launch_bounds__(256, 2) void flash_kernel(
    const ushort* __restrict__ qb, const ushort* __restrict__ kbuf,
    const ushort* __restrict__ whb, const ushort* __restrict__ Xb,
    const ushort* __restrict__ PZ, const ushort* __restrict__ vTb,
    ushort* __restrict__ oall)
{
  int h = blockIdx.x;
  int ty = blockIdx.y;
  int ri = (ty < 8) ? (15 - ty) : (ty - 8);   // blocks n,n+256: ri & 15-ri → 17 iters/CU
  int r0 = ri * 64;
  const ushort* q_h = qb + (long)(h >> 1) * 64;
  const ushort* k_h = kbuf + (long)(h >> 1) * 64;
  const ushort* wh_h = whb + (long)h * TTD * HDIM;
  const ushort* X_h = Xb + (long)h * TTD * TTD;
  const ushort* pz = PZ + ((long)h * 15 + (ri - 1)) * TTD * HDIM;  // valid iff ri>0
  const ushort* v_h = vTb + (long)(h >> 1) * 64 * TTD;

  __shared__ ushort QWD[64 * LS];
  __shared__ ushort PT[2][64 * LS];

  int tid = threadIdx.x, w = tid >> 6, l = tid & 63;
  int quad = l >> 4, lane15 = l & 15;

  bf16x8 aq[2];
  #pragma unroll
  for (int s = 0; s < 2; ++s)
    aq[s] = *(const bf16x8*)&q_h[(long)(r0 + w * 16 + lane15) * DDM + s * 32 + quad * 8];

  // QWD = -incl(q.wh^T), staged [i][t]
  {
    f32x4 t4[4] = {};
    #pragma unroll
    for (int s = 0; s < 2; ++s)
      #pragma unroll
      for (int f = 0; f < 4; ++f) {
        bf16x8 bf = *(const bf16x8*)&wh_h[(long)(r0 + f * 16 + lane15) * HDIM + s * 32 + quad * 8];
        t4[f] = MFMA16(aq[s], bf, t4[f]);
      }
    #pragma unroll
    for (int f = 0; f < 4; ++f)
      #pragma unroll
      for (int r = 0; r < 4; ++r) {
        int i = w * 16 + quad * 4 + r, t = f * 16 + lane15;
        QWD[i * LS + t] = (i >= t) ? f2b(-t4[f][r]) : (ushort)0;
      }
  }
  __syncthreads();

  f32x4 O[4] = {};
  float m[4], lsum[4];
  #pragma unroll
  for (int r = 0; r < 4; ++r) { m[r] = -1e30f; lsum[r] = 0.f; }

  // prefetch registers for jb=0
  bf16x8 fk[8], fx[8], fz[8], fv[8];
  #pragma unroll
  for (int s = 0; s < 2; ++s)
    #pragma unroll
    for (int f = 0; f < 4; ++f) {
      fk[s * 4 + f] = *(const bf16x8*)&k_h[(long)(f * 16 + lane15) * DDM + s * 32 + quad * 8];
      fx[s * 4 + f] = *(const bf16x8*)&X_h[(long)(f * 16 + lane15) * TTD + r0 + s * 32 + quad * 8];
      fv[s * 4 + f] = *(const bf16x8*)&v_h[(long)(f * 16 + lane15) * TTD + s * 32 + quad * 8];
    }
  if (ri > 0) {
    #pragma unroll
    for (int s = 0; s < 2; ++s)
      #pragma unroll
      for (int f = 0; f < 4; ++f)
        fz[s * 4 + f] = *(const bf16x8*)&pz[(long)(f * 16 + lane15) * HDIM + s * 32 + quad * 8];
  }

  for (int jb = 0; jb <= ri; ++jb) {
    f32x4 acc[4] = {};
    #pragma unroll
    for (int s = 0; s < 2; ++s)
      #pragma unroll
      for (int f = 0; f < 4; ++f)
        acc[f] = MFMA16(aq[s], fk[s * 4 + f], acc[f]);
    if (jb < ri) {
      #pragma unroll
      for (int s = 0; s < 2; ++s)
        #pragma unroll
        for (int f = 0; f < 4; ++f)
          acc[f] = MFMA16(aq[s], fz[s * 4 + f], acc[f]);
    }
    #pragma unroll
    for (int s = 0; s < 2; ++s) {
      bf16x8 aw = *(const bf16x8*)&QWD[(w * 16 + lane15) * LS + s * 32 + quad * 8];
      #pragma unroll
      for (int f = 0; f < 4; ++f)
        acc[f] = MFMA16(aw, fx[s * 4 + f], acc[f]);
    }
    // prefetch next jb (clamped addresses; redundant loads on last iter)
    int c0n = (jb + 1 <= ri ? jb + 1 : ri) * 64;
    #pragma unroll
    for (int s = 0; s < 2; ++s)
      #pragma unroll
      for (int f = 0; f < 4; ++f) {
        fk[s * 4 + f] = *(const bf16x8*)&k_h[(long)(c0n + f * 16 + lane15) * DDM + s * 32 + quad * 8];
        fx[s * 4 + f] = *(const bf16x8*)&X_h[(long)(c0n + f * 16 + lane15) * TTD + r0 + s * 32 + quad * 8];
      }
    if (ri > 0) {
      int czn = ((jb + 1 < ri) ? jb + 1 : ri - 1) * 64;
      #pragma unroll
      for (int s = 0; s < 2; ++s)
        #pragma unroll
        for (int f = 0; f < 4; ++f)
          fz[s * 4 + f] = *(const bf16x8*)&pz[(long)(czn + f * 16 + lane15) * HDIM + s * 32 + quad * 8];
    }
    // online softmax
    float rmax[4] = {-3e38f, -3e38f, -3e38f, -3e38f};
    #pragma unroll
    for (int f = 0; f < 4; ++f)
      #pragma unroll
      for (int r = 0; r < 4; ++r) {
        float lv = acc[f][r] * PSCALE;
        if (jb == ri && (f * 16 + lane15) > (w * 16 + quad * 4 + r)) lv = -3e38f;
        acc[f][r] = lv;
        rmax[r] = fmaxf(rmax[r], lv);
      }
    #pragma unroll
    for (int r = 0; r < 4; ++r) {
      rmax[r] = fmaxf(rmax[r], __shfl_xor(rmax[r], 1, 64));
      rmax[r] = fmaxf(rmax[r], __shfl_xor(rmax[r], 2, 64));
      rmax[r] = fmaxf(rmax[r], __shfl_xor(rmax[r], 4, 64));
      rmax[r] = fmaxf(rmax[r], __shfl_xor(rmax[r], 8, 64));
    }
    float alpha[4], rs[4] = {0.f, 0.f, 0.f, 0.f};
    #pragma unroll
    for (int r = 0; r < 4; ++r) {
      float nm = fmaxf(m[r], rmax[r]);
      alpha[r] = __expf(m[r] - nm);
      m[r] = nm;
    }
    #pragma unroll
    for (int f = 0; f < 4; ++f)
      #pragma unroll
      for (int r = 0; r < 4; ++r) {
        float e = __expf(acc[f][r] - m[r]);
        acc[f][r] = e;
        rs[r] += e;
      }
    #pragma unroll
    for (int r = 0; r < 4; ++r) {
      rs[r] += __shfl_xor(rs[r], 1, 64);
      rs[r] += __shfl_xor(rs[r], 2, 64);
      rs[r] += __shfl_xor(rs[r], 4, 64);
      rs[r] += __shfl_xor(rs[r], 8, 64);
      lsum[r] = lsum[r] * alpha[r] + rs[r];
    }
    #pragma unroll
    for (int f = 0; f < 4; ++f)
      #pragma unroll
      for (int r = 0; r < 4; ++r) O[f][r] *= alpha[r];
    // stage P (double-buffered: ONE barrier per iter)
    ushort* PTb = &PT[jb & 1][0];
    #pragma unroll
    for (int f = 0; f < 4; ++f)
      #pragma unroll
      for (int r = 0; r < 4; ++r)
        PTb[(w * 16 + quad * 4 + r) * LS + f * 16 + lane15] = f2b(acc[f][r]);
    __syncthreads();
    #pragma unroll
    for (int s = 0; s < 2; ++s) {
      bf16x8 ap = *(const bf16x8*)&PTb[(w * 16 + lane15) * LS + s * 32 + quad * 8];
      #pragma unroll
      for (int f = 0; f < 4; ++f)
        O[f] = MFMA16(ap, fv[s * 4 + f], O[f]);
    }
    // prefetch v for next jb
    #pragma unroll
    for (int s = 0; s < 2; ++s)
      #pragma unroll
      for (int f = 0; f < 4; ++f)
        fv[s * 4 + f] = *(const bf16x8*)&v_h[(long)(f * 16 + lane15) * TTD + c0n + s * 32 + quad * 8];
  }
  #pragma unroll
  for (int r = 0; r < 4; ++r) lsum[r] = 1.f / lsum[r];
  #pragma unroll
  for (int f = 0; f < 4; ++f)
    #pragma unroll
    for (int r = 0; r < 4; ++r)
      oall[(long)(r0 + w * 16 + quad * 4 + r) * 2048 + h * 64 + f * 16 + lane15] =
          f2b(O[f][r] * lsum[r]);
}

// ---------------- conv(K=3)+SiLU+rotate+normalize -> wh bf16 ----------------
__global__ __launch_bounds__(256) void convdir_kernel(
    const float* __restrict__ w_raw, const float* __restrict__ conv_w,
    const float* __restrict__ omega, const float* __restrict__ phi,
    ushort* __restrict__ whb)
{
  int gid = blockIdx.x * 256 + threadIdx.x;
  int lane = gid & 63;
  int w = gid >> 6;
  int hr = w & 31, t = w >> 5;
  int hkv = hr >> 1, r = hr & 1;
  int cA = hkv * 256 + r * 128 + lane;
  int cB = cA + 64;
  float a = 0.f, b = 0.f;
  #pragma unroll
  for (int i = 0; i < 3; ++i) {
    int tp = t - 2 + i;
    if (tp >= 0) {
      a += w_raw[(long)tp * NOUTW + cA] * conv_w[cA * 3 + i];
      b += w_raw[(long)tp * NOUTW + cB] * conv_w[cB * 3 + i];
    }
  }
  a = a / (1.f + expf(-a));
  b = b / (1.f + expf(-b));
  float th = omega[r] * (float)t + phi[r];
  float wd = a * cosf(th) + b * sinf(th);
  float ss = wd * wd;
  #pragma unroll
  for (int o = 32; o > 0; o >>= 1) ss += __shfl_xor(ss, o, 64);
  float inv = 1.f / sqrtf(ss + 1e-6f);
  whb[((long)hr * TTD + t) * HDIM + lane] = f2b(wd * inv);
}

// ---------------- final GEMM: out = o_all(bf16) @ o_w^T(fp32, in-register cvt) ----------------
__global__ __launch_bounds__(256) void gemm_out_kernel(
    const ushort* __restrict__ A, const float* __restrict__ Bw, float* __restrict__ C)
{
  __shared__ ushort As[64 * 32];
  __shared__ ushort Bs[64 * 32];
  int tid = threadIdx.x, w = tid >> 6, l = tid & 63;
  int quad = l >> 4, lane15 = l & 15;
  int rm = blockIdx.y * 64, cn = blockIdx.x * 64;
  int row = tid >> 2, ch = (tid & 3) * 8;
  f32x4 acc[4] = {};
  for (int k0 = 0; k0 < 2048; k0 += 32) {
    gload_lds16(A + (long)(rm + row) * 2048 + k0 + ch, &As[tid * 8]);
    float4 f0 = *(const float4*)&Bw[(long)(cn + row) * 2048 + k0 + ch];
    float4 f1 = *(const float4*)&Bw[(long)(cn + row) * 2048 + k0 + ch + 4];
    ushort tmp[8];
    tmp[0] = f2b(f0.x); tmp[1] = f2b(f0.y); tmp[2] = f2b(f0.z); tmp[3] = f2b(f0.w);
    tmp[4] = f2b(f1.x); tmp[5] = f2b(f1.y); tmp[6] = f2b(f1.z); tmp[7] = f2b(f1.w);
    *(uint4*)&Bs[tid * 8] = *(const uint4*)&tmp[0];
    __syncthreads();
    bf16x8 af = *(const bf16x8*)&As[(w * 16 + lane15) * 32 + quad * 8];
    #pragma unroll
    for (int f = 0; f < 4; ++f) {
      bf16x8 bf = *(const bf16x8*)&Bs[(f * 16 + lane15) * 32 + quad * 8];
      acc[f] = MFMA16(af, bf, acc[f]);
    }
    __syncthreads();
  }
  int orow = rm + w * 16 + quad * 4;
  #pragma unroll
  for (int f = 0; f < 4; ++f)
    #pragma unroll
    for (int r = 0; r < 4; ++r)
      C[(long)(orow + r) * DDM + cn + f * 16 + lane15] = acc[f][r];
}

// ---------------- host ----------------
extern "C" void kernel_launch(void* const* d_in, const int* in_sizes, int n_in,
                              void* d_out, int out_size, void* d_ws, size_t ws_size,
                              hipStream_t stream) {
  const float* hs     = (const float*)d_in[0];
  const float* q_w    = (const float*)d_in[1];
  const float* k_w    = (const float*)d_in[2];
  const float* v_w    = (const float*)d_in[3];
  const float* w1     = (const float*)d_in[4];
  const float* w2     = (const float*)d_in[5];
  const float* conv_w = (const float*)d_in[6];
  const float* bt_w   = (const float*)d_in[7];
  const float* bt_b   = (const float*)d_in[8];
  const float* o_w    = (const float*)d_in[9];
  const float* omega  = (const float*)d_in[10];
  const float* phi    = (const float*)d_in[11];
  float* out = (float*)d_out;
  char* ws = (char*)d_ws;

  ushort* Xb     = (ushort*)(ws + OFF_X);
  ushort* PZ     = (ushort*)(ws + OFF_PZ);
  ushort* hs_b   = (ushort*)(ws + OFF_HSB);
  ushort* qw_wb  = (ushort*)(ws + OFF_QWW);
  ushort* kw_wb  = (ushort*)(ws + OFF_KWW);
  ushort* vw_wb  = (ushort*)(ws + OFF_VWW);
  ushort* w2_b   = (ushort*)(ws + OFF_W2B);
  ushort* wlow_b = (ushort*)(ws + OFF_WLOWB);
  float*  w_raw  = (float*)(ws + OFF_WRAW);
  ushort* TB     = (ushort*)(ws + OFF_TB);
  ushort* o_all  = (ushort*)(ws + OFF_OALL);
  ushort* YB     = (ushort*)(ws + OFF_YB);
  ushort* wh_b   = (ushort*)(ws + OFF_WHB);
  ushort* q_b    = (ushort*)(ws + OFF_QB);
  ushort* k_b    = (ushort*)(ws + OFF_KB);
  ushort* vT_b   = (ushort*)(ws + OFF_VTB);
  float*  beta   = (float*)(ws + OFF_BETA);
  ushort* bw_b   = (ushort*)(ws + OFF_BW64);

  // one merged convert launch
  CvtSegs sg;
  sg.src[0] = hs;   sg.dst[0] = hs_b;          sg.cnt[0] = 1048576;
  sg.src[1] = q_w;  sg.dst[1] = qw_wb;         sg.cnt[1] = 1048576;
  sg.src[2] = k_w;  sg.dst[2] = kw_wb;         sg.cnt[2] = 1048576;
  sg.src[3] = v_w;  sg.dst[3] = vw_wb;         sg.cnt[3] = 1048576;
  sg.src[4] = w2;   sg.dst[4] = w2_b;          sg.cnt[4] = 131072;
  sg.src[5] = bt_w; sg.dst[5] = bw_b;          sg.cnt[5] = 32768;
  sg.src[6] = w1;   sg.dst[6] = bw_b + 32768;  sg.cnt[6] = 32768;
  cvt_all_kernel<<<dim3(4288), 256, 0, stream>>>(sg);

  smallproj_kernel<<<dim3(16), 256, 0, stream>>>(hs_b, bw_b, bt_b, beta, wlow_b);
  qkv_kernel<<<dim3(16, 16, 3), 256, 0, stream>>>(hs_b, qw_wb, kw_wb, vw_wb, q_b, k_b, vT_b);
  wraw_kernel<<<dim3(64, 16), 256, 0, stream>>>(wlow_b, w2_b, w_raw);
  convdir_kernel<<<dim3(8192), 256, 0, stream>>>(w_raw, conv_w, omega, phi, wh_b);

  solveA_kernel<<<dim3(16, 32), 256, 0, stream>>>(wh_b, beta, TB, YB);
  solveB_kernel<<<dim3(32, 16), 256, 0, stream>>>(wh_b, k_b, TB, YB, Xb, PZ);
  flash_kernel<<<dim3(32, 16), 256, 0, stream>>>(q_b, k_b, wh_b, Xb, PZ, vT_b, o_all);
  gemm_out_kernel<<<dim3(16, 16), 256, 0, stream>>>(o_all, o_w, out);

  (void)in_sizes; (void)n_in; (void)out_size; (void)ws_size;
}